// Round 1
// baseline (342.297 us; speedup 1.0000x reference)
//
#include <hip/hip_runtime.h>
#include <cstdint>

#define NPTS 2048
#define NB 8
// float32 of (0.45*0.45 computed in float64) -- matches jnp/np scalar cast.
// NOTE: 0.45f*0.45f is 1 ulp LOWER; do not use it.
#define R2C 0.2025f

__device__ __forceinline__ float fmul(float a, float b) { return __fmul_rn(a, b); }
__device__ __forceinline__ float fadd(float a, float b) { return __fadd_rn(a, b); }

// ---------------- K1: per-point features ----------------
// fa[p*64+o]  = relu(W2a·relu(W1a·x+b1a)+b2a)
// fb[p*128+o] = relu(W2b·relu(W1b·x+b1b)+b2b)
// v[(b*128+o)*2048+i] = relu(Wc1·x+bc1)   (o<64; channels 64..127 filled by K2)
__global__ __launch_bounds__(256) void k_features(
    const float* __restrict__ X,
    const float* __restrict__ W1a, const float* __restrict__ b1a,
    const float* __restrict__ W2a, const float* __restrict__ b2a,
    const float* __restrict__ W1b, const float* __restrict__ b1b,
    const float* __restrict__ W2b, const float* __restrict__ b2b,
    const float* __restrict__ Wc1, const float* __restrict__ bc1,
    float* __restrict__ fa, float* __restrict__ fb, float* __restrict__ v)
{
    __shared__ float s[11072];
    float* sW1a = s;          // 96
    float* sb1a = s + 96;     // 32
    float* sW2a = s + 128;    // 2048
    float* sb2a = s + 2176;   // 64
    float* sW1b = s + 2240;   // 192
    float* sb1b = s + 2432;   // 64
    float* sW2b = s + 2496;   // 8192
    float* sb2b = s + 10688;  // 128
    float* sWc1 = s + 10816;  // 192
    float* sbc1 = s + 11008;  // 64
    int tid = threadIdx.x;
    for (int t = tid; t < 96;   t += 256) sW1a[t] = W1a[t];
    for (int t = tid; t < 32;   t += 256) sb1a[t] = b1a[t];
    for (int t = tid; t < 2048; t += 256) sW2a[t] = W2a[t];
    for (int t = tid; t < 64;   t += 256) sb2a[t] = b2a[t];
    for (int t = tid; t < 192;  t += 256) sW1b[t] = W1b[t];
    for (int t = tid; t < 64;   t += 256) sb1b[t] = b1b[t];
    for (int t = tid; t < 8192; t += 256) sW2b[t] = W2b[t];
    for (int t = tid; t < 128;  t += 256) sb2b[t] = b2b[t];
    for (int t = tid; t < 192;  t += 256) sWc1[t] = Wc1[t];
    for (int t = tid; t < 64;   t += 256) sbc1[t] = bc1[t];
    __syncthreads();

    int p = blockIdx.x * 256 + tid;           // 0..16383
    float x0 = X[p * 3 + 0], x1 = X[p * 3 + 1], x2 = X[p * 3 + 2];

    float h[64];
    // branch a
#pragma unroll
    for (int o = 0; o < 32; ++o)
        h[o] = fmaxf(0.f, x0 * sW1a[o * 3] + x1 * sW1a[o * 3 + 1] + x2 * sW1a[o * 3 + 2] + sb1a[o]);
    float* fap = fa + (size_t)p * 64;
#pragma unroll 2
    for (int o = 0; o < 64; ++o) {
        float acc = sb2a[o];
#pragma unroll
        for (int k = 0; k < 32; ++k) acc = fmaf(h[k], sW2a[o * 32 + k], acc);
        fap[o] = fmaxf(0.f, acc);
    }
    // branch b
#pragma unroll 2
    for (int o = 0; o < 64; ++o)
        h[o] = fmaxf(0.f, x0 * sW1b[o * 3] + x1 * sW1b[o * 3 + 1] + x2 * sW1b[o * 3 + 2] + sb1b[o]);
    float* fbp = fb + (size_t)p * 128;
#pragma unroll 2
    for (int o = 0; o < 128; ++o) {
        float acc = sb2b[o];
#pragma unroll
        for (int k = 0; k < 64; ++k) acc = fmaf(h[k], sW2b[o * 64 + k], acc);
        fbp[o] = fmaxf(0.f, acc);
    }
    // conv1 path -> v channels 0..63
    int b = p >> 11, i = p & 2047;
    float* vb = v + (size_t)b * 128 * NPTS + i;
#pragma unroll 2
    for (int o = 0; o < 64; ++o)
        vb[(size_t)o * NPTS] =
            fmaxf(0.f, x0 * sWc1[o * 3] + x1 * sWc1[o * 3 + 1] + x2 * sWc1[o * 3 + 2] + sbc1[o]);
}

// ---------------- K2: ball query + neighborhood max-pool ----------------
// One wave (64 lanes) per point. 4 waves / block share x[b] in LDS.
__global__ __launch_bounds__(256) void k_neighbors(
    const float* __restrict__ X, const float* __restrict__ fa,
    const float* __restrict__ fb, float* __restrict__ v, float* __restrict__ out)
{
    __shared__ float xs[NPTS * 3];
    __shared__ unsigned long long masks[4][32];
    int wid = threadIdx.x >> 6, lane = threadIdx.x & 63;
    int p = blockIdx.x * 4 + wid;
    int b = p >> 11, i = p & 2047;

    // cooperative stage of x[b] (24KB), float4-coalesced
    const float4* xsrc = (const float4*)(X + (size_t)b * NPTS * 3);
    float4* xdst = (float4*)xs;
    for (int t = threadIdx.x; t < (NPTS * 3 / 4); t += 256) xdst[t] = xsrc[t];
    __syncthreads();

    float n0 = xs[i * 3], n1 = xs[i * 3 + 1], n2 = xs[i * 3 + 2];
    float nn = fadd(fadd(fmul(n0, n0), fmul(n1, n1)), fmul(n2, n2));

    // 32 ballot words of in-radius mask (exact numpy arithmetic, no FMA)
    for (int w = 0; w < 32; ++w) {
        int m = (w << 6) | lane;
        float y0 = xs[m * 3], y1 = xs[m * 3 + 1], y2 = xs[m * 3 + 2];
        float dot = fadd(fadd(fmul(n0, y0), fmul(n1, y1)), fmul(n2, y2));
        float mm  = fadd(fadd(fmul(y0, y0), fmul(y1, y1)), fmul(y2, y2));
        float d   = fadd(fadd(fmul(-2.0f, dot), nn), mm);
        unsigned long long bm = __ballot(!(d > R2C));
        if (lane == w) masks[wid][w] = bm;
    }
    __syncthreads();   // make per-wave mask words visible across lanes

    // ---- scan 1: first 64 in-radius -> max of fa ----
    {
        const float* fab = fa + (size_t)b * NPTS * 64;
        float g1 = -1e30f;
        int remaining = 64;
        for (int w = 0; w < 32 && remaining; ++w) {
            unsigned long long word = masks[wid][w];
            while (word && remaining) {
                int pb = __builtin_ctzll(word);
                word &= word - 1;
                --remaining;
                g1 = fmaxf(g1, fab[((size_t)((w << 6) | pb)) * 64 + lane]);
            }
        }
        v[((size_t)b * 128 + 64 + lane) * NPTS + i] = g1;
    }
    // ---- scan 2: first 128 in-radius -> max of fb -> out channels 256..383 ----
    {
        const float* fbb = fb + (size_t)b * NPTS * 128;
        float g2a = -1e30f, g2b = -1e30f;
        int remaining = 128;
        for (int w = 0; w < 32 && remaining; ++w) {
            unsigned long long word = masks[wid][w];
            while (word && remaining) {
                int pb = __builtin_ctzll(word);
                word &= word - 1;
                --remaining;
                const float* row = fbb + ((size_t)((w << 6) | pb)) * 128;
                g2a = fmaxf(g2a, row[lane]);
                g2b = fmaxf(g2b, row[lane + 64]);
            }
        }
        size_t ob = ((size_t)b * 384 + 256) * NPTS + i;
        out[ob + (size_t)lane * NPTS] = g2a;
        out[ob + (size_t)(lane + 64) * NPTS] = g2b;
    }
}

// ---------------- K3: 256x128 pointwise conv over v -> out channels 0..255 ----
__global__ __launch_bounds__(256) void k_conv2(
    const float* __restrict__ v, const float* __restrict__ Wc2,
    const float* __restrict__ bc2, float* __restrict__ out)
{
    __shared__ float vt[128 * 32];
    int bb = blockIdx.x >> 6;          // batch
    int nt = (blockIdx.x & 63) << 5;   // n-tile base (32 points)
    const float* vb = v + (size_t)bb * 128 * NPTS + nt;
    for (int idx = threadIdx.x; idx < 128 * 32; idx += 256) {
        int k = idx >> 5, n = idx & 31;
        vt[idx] = vb[(size_t)k * NPTS + n];
    }
    __syncthreads();

    int o = threadIdx.x;               // 0..255 output channel
    const float* wrow = Wc2 + o * 128;
    float bias = bc2[o];
    float acc[32];
#pragma unroll
    for (int n = 0; n < 32; ++n) acc[n] = bias;

    for (int k4 = 0; k4 < 128; k4 += 4) {
        float4 wv = *(const float4*)(wrow + k4);
        const float wk[4] = {wv.x, wv.y, wv.z, wv.w};
#pragma unroll
        for (int kk = 0; kk < 4; ++kk) {
            float w = wk[kk];
            const float* vr = vt + (k4 + kk) * 32;
#pragma unroll
            for (int n4 = 0; n4 < 8; ++n4) {
                float4 vv = *(const float4*)(vr + n4 * 4);
                acc[n4 * 4 + 0] = fmaf(w, vv.x, acc[n4 * 4 + 0]);
                acc[n4 * 4 + 1] = fmaf(w, vv.y, acc[n4 * 4 + 1]);
                acc[n4 * 4 + 2] = fmaf(w, vv.z, acc[n4 * 4 + 2]);
                acc[n4 * 4 + 3] = fmaf(w, vv.w, acc[n4 * 4 + 3]);
            }
        }
    }
    float* ob = out + ((size_t)bb * 384 + o) * NPTS + nt;
#pragma unroll
    for (int n4 = 0; n4 < 8; ++n4) {
        float4 r;
        r.x = fmaxf(0.f, acc[n4 * 4 + 0]);
        r.y = fmaxf(0.f, acc[n4 * 4 + 1]);
        r.z = fmaxf(0.f, acc[n4 * 4 + 2]);
        r.w = fmaxf(0.f, acc[n4 * 4 + 3]);
        *(float4*)(ob + n4 * 4) = r;
    }
}

extern "C" void kernel_launch(void* const* d_in, const int* in_sizes, int n_in,
                              void* d_out, int out_size, void* d_ws, size_t ws_size,
                              hipStream_t stream) {
    const float* X   = (const float*)d_in[0];
    const float* W1a = (const float*)d_in[1];
    const float* b1a = (const float*)d_in[2];
    const float* W2a = (const float*)d_in[3];
    const float* b2a = (const float*)d_in[4];
    const float* W1b = (const float*)d_in[5];
    const float* b1b = (const float*)d_in[6];
    const float* W2b = (const float*)d_in[7];
    const float* b2b = (const float*)d_in[8];
    const float* Wc1 = (const float*)d_in[9];
    const float* bc1 = (const float*)d_in[10];
    const float* Wc2 = (const float*)d_in[11];
    const float* bc2 = (const float*)d_in[12];
    float* out = (float*)d_out;

    // workspace layout (20 MB total)
    float* fa = (float*)d_ws;                         // 8*2048*64
    float* fb = fa + (size_t)NB * NPTS * 64;          // 8*2048*128
    float* v  = fb + (size_t)NB * NPTS * 128;         // 8*128*2048

    k_features<<<NB * NPTS / 256, 256, 0, stream>>>(X, W1a, b1a, W2a, b2a,
                                                    W1b, b1b, W2b, b2b, Wc1, bc1,
                                                    fa, fb, v);
    k_neighbors<<<NB * NPTS / 4, 256, 0, stream>>>(X, fa, fb, v, out);
    k_conv2<<<NB * (NPTS / 32), 256, 0, stream>>>(v, Wc2, bc2, out);
}

// Round 2
// 262.224 us; speedup vs baseline: 1.3054x; 1.3054x over previous
//
#include <hip/hip_runtime.h>
#include <cstdint>

#define NPTS 2048
#define NB 8
// float32 of (0.45*0.45 computed in float64) -- matches jnp/np scalar cast.
// NOTE: 0.45f*0.45f is 1 ulp LOWER; do not use it.
#define R2C 0.2025f

__device__ __forceinline__ float fmul(float a, float b) { return __fmul_rn(a, b); }
__device__ __forceinline__ float fadd(float a, float b) { return __fadd_rn(a, b); }

// ---------------- K1: per-point features (+ Wc2 transpose) ----------------
// fa[p*64+o]  = relu(W2a·relu(W1a·x+b1a)+b2a)
// fb[p*128+o] = relu(W2b·relu(W1b·x+b1b)+b2b)
// v[(b*128+o)*2048+i] = relu(Wc1·x+bc1)   (o<64; channels 64..127 filled by K2)
// wT[k*256+o] = Wc2[o*128+k]
__global__ __launch_bounds__(256) void k_features(
    const float* __restrict__ X,
    const float* __restrict__ W1a, const float* __restrict__ b1a,
    const float* __restrict__ W2a, const float* __restrict__ b2a,
    const float* __restrict__ W1b, const float* __restrict__ b1b,
    const float* __restrict__ W2b, const float* __restrict__ b2b,
    const float* __restrict__ Wc1, const float* __restrict__ bc1,
    const float* __restrict__ Wc2,
    float* __restrict__ fa, float* __restrict__ fb, float* __restrict__ v,
    float* __restrict__ wT)
{
    __shared__ float s[11072];
    float* sW1a = s;          // 96
    float* sb1a = s + 96;     // 32
    float* sW2a = s + 128;    // 2048
    float* sb2a = s + 2176;   // 64
    float* sW1b = s + 2240;   // 192
    float* sb1b = s + 2432;   // 64
    float* sW2b = s + 2496;   // 8192
    float* sb2b = s + 10688;  // 128
    float* sWc1 = s + 10816;  // 192
    float* sbc1 = s + 11008;  // 64
    int tid = threadIdx.x;
    for (int t = tid; t < 96;   t += 256) sW1a[t] = W1a[t];
    for (int t = tid; t < 32;   t += 256) sb1a[t] = b1a[t];
    for (int t = tid; t < 2048; t += 256) sW2a[t] = W2a[t];
    for (int t = tid; t < 64;   t += 256) sb2a[t] = b2a[t];
    for (int t = tid; t < 192;  t += 256) sW1b[t] = W1b[t];
    for (int t = tid; t < 64;   t += 256) sb1b[t] = b1b[t];
    for (int t = tid; t < 8192; t += 256) sW2b[t] = W2b[t];
    for (int t = tid; t < 128;  t += 256) sb2b[t] = b2b[t];
    for (int t = tid; t < 192;  t += 256) sWc1[t] = Wc1[t];
    for (int t = tid; t < 64;   t += 256) sbc1[t] = bc1[t];

    // Wc2 transpose slice for this block (coalesced read, scattered 4B write)
    {
        int base = blockIdx.x * 512;
        for (int e = tid; e < 512; e += 256) {
            int idx = base + e;
            int o = idx >> 7, k = idx & 127;
            wT[k * 256 + o] = Wc2[idx];
        }
    }
    __syncthreads();

    int p = blockIdx.x * 256 + tid;           // 0..16383
    float x0 = X[p * 3 + 0], x1 = X[p * 3 + 1], x2 = X[p * 3 + 2];

    float h[64];
    // branch a
#pragma unroll
    for (int o = 0; o < 32; ++o)
        h[o] = fmaxf(0.f, x0 * sW1a[o * 3] + x1 * sW1a[o * 3 + 1] + x2 * sW1a[o * 3 + 2] + sb1a[o]);
    float* fap = fa + (size_t)p * 64;
#pragma unroll 2
    for (int o = 0; o < 64; ++o) {
        float acc = sb2a[o];
#pragma unroll
        for (int k = 0; k < 32; ++k) acc = fmaf(h[k], sW2a[o * 32 + k], acc);
        fap[o] = fmaxf(0.f, acc);
    }
    // branch b
#pragma unroll 2
    for (int o = 0; o < 64; ++o)
        h[o] = fmaxf(0.f, x0 * sW1b[o * 3] + x1 * sW1b[o * 3 + 1] + x2 * sW1b[o * 3 + 2] + sb1b[o]);
    float* fbp = fb + (size_t)p * 128;
#pragma unroll 2
    for (int o = 0; o < 128; ++o) {
        float acc = sb2b[o];
#pragma unroll
        for (int k = 0; k < 64; ++k) acc = fmaf(h[k], sW2b[o * 64 + k], acc);
        fbp[o] = fmaxf(0.f, acc);
    }
    // conv1 path -> v channels 0..63
    int b = p >> 11, i = p & 2047;
    float* vb = v + (size_t)b * 128 * NPTS + i;
#pragma unroll 2
    for (int o = 0; o < 64; ++o)
        vb[(size_t)o * NPTS] =
            fmaxf(0.f, x0 * sWc1[o * 3] + x1 * sWc1[o * 3 + 1] + x2 * sWc1[o * 3 + 2] + sbc1[o]);
}

// ---------------- K2: ball query + neighborhood max-pool ----------------
// One wave (64 lanes) per point; 4 waves/block share x[b] in LDS.
// blockIdx & 7 = batch  -> batch-per-XCD L2 affinity under round-robin dispatch.
__global__ __launch_bounds__(256) void k_neighbors(
    const float* __restrict__ X, const float* __restrict__ fa,
    const float* __restrict__ fb, float* __restrict__ v, float* __restrict__ out)
{
    __shared__ float xs[NPTS * 3];
    __shared__ unsigned short nbr[4][128];
    int wid = threadIdx.x >> 6, lane = threadIdx.x & 63;
    int b = blockIdx.x & 7;
    int i = (blockIdx.x >> 3) * 4 + wid;      // point index within batch

    // cooperative stage of x[b] (24KB), float4-coalesced
    const float4* xsrc = (const float4*)(X + (size_t)b * NPTS * 3);
    float4* xdst = (float4*)xs;
    for (int t = threadIdx.x; t < (NPTS * 3 / 4); t += 256) xdst[t] = xsrc[t];
    __syncthreads();

    float n0 = xs[i * 3], n1 = xs[i * 3 + 1], n2 = xs[i * 3 + 2];
    float nn = fadd(fadd(fmul(n0, n0), fmul(n1, n1)), fmul(n2, n2));

    // 32 ballot words; lane w keeps word w (ballot result is wave-uniform)
    unsigned long long myword = 0;
    for (int w = 0; w < 32; ++w) {
        int m = (w << 6) | lane;
        float y0 = xs[m * 3], y1 = xs[m * 3 + 1], y2 = xs[m * 3 + 2];
        float dot = fadd(fadd(fmul(n0, y0), fmul(n1, y1)), fmul(n2, y2));
        float mm  = fadd(fadd(fmul(y0, y0), fmul(y1, y1)), fmul(y2, y2));
        float d   = fadd(fadd(fmul(-2.0f, dot), nn), mm);
        unsigned long long bm = __ballot(!(d > R2C));
        if (lane == w) myword = bm;
    }

    // parallel decode: lane w computes rank base via prefix-sum of popcounts,
    // then emits its word's indices (ascending) into the shared list.
    int cnt = (lane < 32) ? __popcll(myword) : 0;
    int incl = cnt;
#pragma unroll
    for (int d = 1; d < 32; d <<= 1) {
        int t = __shfl_up(incl, d, 64);
        if (lane >= d) incl += t;
    }
    int pre = incl - cnt;
    if (lane < 32 && cnt && pre < 128) {
        unsigned long long word = myword;
        int r = pre;
        while (word && r < 128) {
            int pb = __builtin_ctzll(word);
            word &= word - 1;
            nbr[wid][r++] = (unsigned short)((lane << 6) | pb);
        }
    }
    int total = __shfl(incl, 31, 64);
    int c1 = min(total, 64);
    int c2 = min(total, 128);
    __syncthreads();

    // ---- pool 1: first 64 in-radius -> max of fa (lane = channel) ----
    {
        const float* fab = fa + (size_t)b * NPTS * 64 + lane;
        float g1 = -1e30f;
        int j = 0;
        for (; j + 4 <= c1; j += 4) {
            ushort4 q = *(const ushort4*)&nbr[wid][j];   // uniform LDS read
            float a0 = fab[(size_t)q.x * 64];
            float a1 = fab[(size_t)q.y * 64];
            float a2 = fab[(size_t)q.z * 64];
            float a3 = fab[(size_t)q.w * 64];
            g1 = fmaxf(fmaxf(fmaxf(g1, a0), fmaxf(a1, a2)), a3);
        }
        for (; j < c1; ++j) g1 = fmaxf(g1, fab[(size_t)nbr[wid][j] * 64]);
        v[((size_t)b * 128 + 64 + lane) * NPTS + i] = g1;
    }
    // ---- pool 2: first 128 in-radius -> max of fb (lane = channel pair) ----
    {
        const float2* fbb = (const float2*)(fb + (size_t)b * NPTS * 128) + lane;
        float2 g2; g2.x = -1e30f; g2.y = -1e30f;
        int j = 0;
        for (; j + 4 <= c2; j += 4) {
            ushort4 q = *(const ushort4*)&nbr[wid][j];
            float2 a0 = fbb[(size_t)q.x * 64];
            float2 a1 = fbb[(size_t)q.y * 64];
            float2 a2 = fbb[(size_t)q.z * 64];
            float2 a3 = fbb[(size_t)q.w * 64];
            g2.x = fmaxf(fmaxf(fmaxf(g2.x, a0.x), fmaxf(a1.x, a2.x)), a3.x);
            g2.y = fmaxf(fmaxf(fmaxf(g2.y, a0.y), fmaxf(a1.y, a2.y)), a3.y);
        }
        for (; j < c2; ++j) {
            float2 a = fbb[(size_t)nbr[wid][j] * 64];
            g2.x = fmaxf(g2.x, a.x); g2.y = fmaxf(g2.y, a.y);
        }
        size_t ob = ((size_t)b * 384 + 256 + 2 * lane) * NPTS + i;
        out[ob] = g2.x;
        out[ob + NPTS] = g2.y;
    }
}

// ---------------- K3: 256x128 pointwise conv over v -> out channels 0..255 ----
// thread = output channel; v-tile addresses are wave-uniform -> scalar loads.
__global__ __launch_bounds__(256) void k_conv2(
    const float* __restrict__ v, const float* __restrict__ wT,
    const float* __restrict__ bc2, float* __restrict__ out)
{
    __shared__ float tr[256 * 33];             // padded transpose buffer
    int b = blockIdx.x & 7;                    // batch-per-XCD affinity
    int nt = (blockIdx.x >> 3) << 5;           // 32-point tile
    int o = threadIdx.x;
    const float* vb = v + (size_t)b * 128 * NPTS + nt;

    float bias = bc2[o];
    float acc[32];
#pragma unroll
    for (int n = 0; n < 32; ++n) acc[n] = bias;

    for (int k = 0; k < 128; ++k) {
        float w = wT[k * 256 + o];             // coalesced 256B
        const float4* vr = (const float4*)(vb + (size_t)k * NPTS);  // uniform
#pragma unroll
        for (int q = 0; q < 8; ++q) {
            float4 a = vr[q];
            acc[q * 4 + 0] = fmaf(w, a.x, acc[q * 4 + 0]);
            acc[q * 4 + 1] = fmaf(w, a.y, acc[q * 4 + 1]);
            acc[q * 4 + 2] = fmaf(w, a.z, acc[q * 4 + 2]);
            acc[q * 4 + 3] = fmaf(w, a.w, acc[q * 4 + 3]);
        }
    }

    // transpose through LDS for coalesced stores
#pragma unroll
    for (int n = 0; n < 32; ++n) tr[o * 33 + n] = fmaxf(0.f, acc[n]);
    __syncthreads();
    int n = threadIdx.x & 31, og = threadIdx.x >> 5;   // 8 channel groups
    float* ob = out + ((size_t)b * 384) * NPTS + nt + n;
#pragma unroll 4
    for (int c = 0; c < 32; ++c) {
        int ch = og * 32 + c;
        ob[(size_t)ch * NPTS] = tr[ch * 33 + n];
    }
}

extern "C" void kernel_launch(void* const* d_in, const int* in_sizes, int n_in,
                              void* d_out, int out_size, void* d_ws, size_t ws_size,
                              hipStream_t stream) {
    const float* X   = (const float*)d_in[0];
    const float* W1a = (const float*)d_in[1];
    const float* b1a = (const float*)d_in[2];
    const float* W2a = (const float*)d_in[3];
    const float* b2a = (const float*)d_in[4];
    const float* W1b = (const float*)d_in[5];
    const float* b1b = (const float*)d_in[6];
    const float* W2b = (const float*)d_in[7];
    const float* b2b = (const float*)d_in[8];
    const float* Wc1 = (const float*)d_in[9];
    const float* bc1 = (const float*)d_in[10];
    const float* Wc2 = (const float*)d_in[11];
    const float* bc2 = (const float*)d_in[12];
    float* out = (float*)d_out;

    // workspace layout (~20.1 MB)
    float* fa = (float*)d_ws;                         // 8*2048*64
    float* fb = fa + (size_t)NB * NPTS * 64;          // 8*2048*128
    float* v  = fb + (size_t)NB * NPTS * 128;         // 8*128*2048
    float* wT = v  + (size_t)NB * 128 * NPTS;         // 128*256

    k_features<<<NB * NPTS / 256, 256, 0, stream>>>(X, W1a, b1a, W2a, b2a,
                                                    W1b, b1b, W2b, b2b, Wc1, bc1,
                                                    Wc2, fa, fb, v, wT);
    k_neighbors<<<NB * NPTS / 4, 256, 0, stream>>>(X, fa, fb, v, out);
    k_conv2<<<NB * (NPTS / 32), 256, 0, stream>>>(v, wT, bc2, out);
}

// Round 3
// 255.165 us; speedup vs baseline: 1.3415x; 1.0277x over previous
//
#include <hip/hip_runtime.h>
#include <cstdint>

#define NPTS 2048
#define NB 8
// float32 of (0.45*0.45 computed in float64) -- matches jnp/np scalar cast.
// NOTE: 0.45f*0.45f is 1 ulp LOWER; do not use it.
#define R2C 0.2025f

__device__ __forceinline__ float fmul(float a, float b) { return __fmul_rn(a, b); }
__device__ __forceinline__ float fadd(float a, float b) { return __fadd_rn(a, b); }

// ---------------- K1: per-point features (+ Wc2 transpose) ----------------
// No LDS: all weight reads are wave-uniform -> s_load, FMA with SGPR operand.
// 512 threads = 8 waves; wave q handles channel slice q; 64 points/block.
__global__ __launch_bounds__(512) void k_features(
    const float* __restrict__ X,
    const float* __restrict__ W1a, const float* __restrict__ b1a,
    const float* __restrict__ W2a, const float* __restrict__ b2a,
    const float* __restrict__ W1b, const float* __restrict__ b1b,
    const float* __restrict__ W2b, const float* __restrict__ b2b,
    const float* __restrict__ Wc1, const float* __restrict__ bc1,
    const float* __restrict__ Wc2,
    float* __restrict__ fa, float* __restrict__ fb, float* __restrict__ v,
    float* __restrict__ wT)
{
    int tid = threadIdx.x;
    int q = __builtin_amdgcn_readfirstlane(tid >> 6);   // wave id 0..7 (SGPR)
    int lp = tid & 63;
    int p = blockIdx.x * 64 + lp;                        // 0..16383
    int b = p >> 11, i = p & 2047;

    // Wc2 transpose: 256 blocks x 128 elements covers 256*128
    if (tid < 128) {
        int idx = blockIdx.x * 128 + tid;
        int o = idx >> 7, k = idx & 127;
        wT[k * 256 + o] = Wc2[idx];
    }

    float x0 = X[p * 3 + 0], x1 = X[p * 3 + 1], x2 = X[p * 3 + 2];

    float h[64];
    // ---- branch a: h (all 32), then 8 channels (q*8..q*8+7) ----
#pragma unroll
    for (int o = 0; o < 32; ++o)
        h[o] = fmaxf(0.f, x0 * W1a[o * 3] + x1 * W1a[o * 3 + 1] + x2 * W1a[o * 3 + 2] + b1a[o]);
    float* fap = fa + (size_t)p * 64;
#pragma unroll
    for (int oo = 0; oo < 8; ++oo) {
        int o = q * 8 + oo;
        float acc = b2a[o];
#pragma unroll
        for (int k = 0; k < 32; ++k) acc = fmaf(h[k], W2a[o * 32 + k], acc);
        fap[o] = fmaxf(0.f, acc);
    }
    // ---- branch b: h (all 64), then 16 channels (q*16..q*16+15) ----
#pragma unroll
    for (int o = 0; o < 64; ++o)
        h[o] = fmaxf(0.f, x0 * W1b[o * 3] + x1 * W1b[o * 3 + 1] + x2 * W1b[o * 3 + 2] + b1b[o]);
    float* fbp = fb + (size_t)p * 128;
#pragma unroll
    for (int oo = 0; oo < 16; ++oo) {
        int o = q * 16 + oo;
        float acc = b2b[o];
#pragma unroll
        for (int k = 0; k < 64; ++k) acc = fmaf(h[k], W2b[o * 64 + k], acc);
        fbp[o] = fmaxf(0.f, acc);
    }
    // ---- conv1 path -> v channels q*8..q*8+7 ----
    float* vb = v + (size_t)b * 128 * NPTS + i;
#pragma unroll
    for (int oo = 0; oo < 8; ++oo) {
        int o = q * 8 + oo;
        vb[(size_t)o * NPTS] =
            fmaxf(0.f, x0 * Wc1[o * 3] + x1 * Wc1[o * 3 + 1] + x2 * Wc1[o * 3 + 2] + bc1[o]);
    }
}

// ---------------- K2: ball query + neighborhood max-pool ----------------
// One wave per point; 16 waves (1024 threads) per block share x[b] in LDS.
// 28KB LDS -> 2 blocks/CU = 32 waves/CU (100% occupancy).
__global__ __launch_bounds__(1024) void k_neighbors(
    const float* __restrict__ X, const float* __restrict__ fa,
    const float* __restrict__ fb, float* __restrict__ v, float* __restrict__ out)
{
    __shared__ float xs0[NPTS], xs1[NPTS], xs2[NPTS];
    __shared__ unsigned short nbr[16][128];
    int tid = threadIdx.x;
    int wid = tid >> 6, lane = tid & 63;
    int b = blockIdx.x & 7;                       // batch-per-XCD L2 affinity
    int i = (blockIdx.x >> 3) * 16 + wid;         // point index within batch

    // stage x[b] as SoA (24KB)
    const float* Xb = X + (size_t)b * NPTS * 3;
    for (int t = tid; t < NPTS; t += 1024) {
        xs0[t] = Xb[3 * t]; xs1[t] = Xb[3 * t + 1]; xs2[t] = Xb[3 * t + 2];
    }
    __syncthreads();

    float n0 = xs0[i], n1 = xs1[i], n2 = xs2[i];
    float nn = fadd(fadd(fmul(n0, n0), fmul(n1, n1)), fmul(n2, n2));

    // 32 ballot words; lane w keeps word w
    unsigned long long myword = 0;
    for (int w = 0; w < 32; ++w) {
        int m = (w << 6) | lane;
        float y0 = xs0[m], y1 = xs1[m], y2 = xs2[m];
        float dot = fadd(fadd(fmul(n0, y0), fmul(n1, y1)), fmul(n2, y2));
        float mm  = fadd(fadd(fmul(y0, y0), fmul(y1, y1)), fmul(y2, y2));
        float d   = fadd(fadd(fmul(-2.0f, dot), nn), mm);
        unsigned long long bm = __ballot(!(d > R2C));
        if (lane == w) myword = bm;
    }

    // parallel decode: prefix-sum of per-word popcounts -> rank base
    int cnt = (lane < 32) ? __popcll(myword) : 0;
    int incl = cnt;
#pragma unroll
    for (int d = 1; d < 32; d <<= 1) {
        int t = __shfl_up(incl, d, 64);
        if (lane >= d) incl += t;
    }
    int pre = incl - cnt;
    if (lane < 32 && cnt && pre < 128) {
        unsigned long long word = myword;
        int r = pre;
        while (word && r < 128) {
            int pb = __builtin_ctzll(word);
            word &= word - 1;
            nbr[wid][r++] = (unsigned short)((lane << 6) | pb);
        }
    }
    int total = __shfl(incl, 31, 64);
    int c1 = min(total, 64);
    int c2 = min(total, 128);
    __syncthreads();

    // ---- pool 1: first 64 -> max of fa (lane = channel), unroll 8 ----
    {
        const float* fab = fa + (size_t)b * NPTS * 64 + lane;
        float g1 = -1e30f;
        int j = 0;
        for (; j + 8 <= c1; j += 8) {
            ushort4 qa = *(const ushort4*)&nbr[wid][j];
            ushort4 qb = *(const ushort4*)&nbr[wid][j + 4];
            float a0 = fab[(size_t)qa.x * 64];
            float a1 = fab[(size_t)qa.y * 64];
            float a2 = fab[(size_t)qa.z * 64];
            float a3 = fab[(size_t)qa.w * 64];
            float a4 = fab[(size_t)qb.x * 64];
            float a5 = fab[(size_t)qb.y * 64];
            float a6 = fab[(size_t)qb.z * 64];
            float a7 = fab[(size_t)qb.w * 64];
            g1 = fmaxf(g1, fmaxf(fmaxf(fmaxf(a0, a1), fmaxf(a2, a3)),
                                 fmaxf(fmaxf(a4, a5), fmaxf(a6, a7))));
        }
        for (; j < c1; ++j) g1 = fmaxf(g1, fab[(size_t)nbr[wid][j] * 64]);
        v[((size_t)b * 128 + 64 + lane) * NPTS + i] = g1;
    }
    // ---- pool 2: first 128 -> max of fb (lane = channel pair), unroll 8 ----
    {
        const float2* fbb = (const float2*)(fb + (size_t)b * NPTS * 128) + lane;
        float2 g2; g2.x = -1e30f; g2.y = -1e30f;
        int j = 0;
        for (; j + 8 <= c2; j += 8) {
            ushort4 qa = *(const ushort4*)&nbr[wid][j];
            ushort4 qb = *(const ushort4*)&nbr[wid][j + 4];
            float2 a0 = fbb[(size_t)qa.x * 64];
            float2 a1 = fbb[(size_t)qa.y * 64];
            float2 a2 = fbb[(size_t)qa.z * 64];
            float2 a3 = fbb[(size_t)qa.w * 64];
            float2 a4 = fbb[(size_t)qb.x * 64];
            float2 a5 = fbb[(size_t)qb.y * 64];
            float2 a6 = fbb[(size_t)qb.z * 64];
            float2 a7 = fbb[(size_t)qb.w * 64];
            g2.x = fmaxf(g2.x, fmaxf(fmaxf(fmaxf(a0.x, a1.x), fmaxf(a2.x, a3.x)),
                                     fmaxf(fmaxf(a4.x, a5.x), fmaxf(a6.x, a7.x))));
            g2.y = fmaxf(g2.y, fmaxf(fmaxf(fmaxf(a0.y, a1.y), fmaxf(a2.y, a3.y)),
                                     fmaxf(fmaxf(a4.y, a5.y), fmaxf(a6.y, a7.y))));
        }
        for (; j < c2; ++j) {
            float2 a = fbb[(size_t)nbr[wid][j] * 64];
            g2.x = fmaxf(g2.x, a.x); g2.y = fmaxf(g2.y, a.y);
        }
        size_t ob = ((size_t)b * 384 + 256 + 2 * lane) * NPTS + i;
        out[ob] = g2.x;
        out[ob + NPTS] = g2.y;
    }
}

// ---------------- K3: 256x128 pointwise conv over v -> out channels 0..255 ----
// thread = output channel; v-tile addresses are blockIdx-uniform -> scalar loads.
__global__ __launch_bounds__(256) void k_conv2(
    const float* __restrict__ v, const float* __restrict__ wT,
    const float* __restrict__ bc2, float* __restrict__ out)
{
    __shared__ float tr[256 * 33];             // padded transpose buffer
    int b = blockIdx.x & 7;                    // batch-per-XCD affinity
    int nt = (blockIdx.x >> 3) << 5;           // 32-point tile
    int o = threadIdx.x;
    const float* vb = v + (size_t)b * 128 * NPTS + nt;

    float bias = bc2[o];
    float acc[32];
#pragma unroll
    for (int n = 0; n < 32; ++n) acc[n] = bias;

    for (int k = 0; k < 128; ++k) {
        float w = wT[k * 256 + o];             // coalesced 256B
        const float4* vr = (const float4*)(vb + (size_t)k * NPTS);  // uniform
#pragma unroll
        for (int qd = 0; qd < 8; ++qd) {
            float4 a = vr[qd];
            acc[qd * 4 + 0] = fmaf(w, a.x, acc[qd * 4 + 0]);
            acc[qd * 4 + 1] = fmaf(w, a.y, acc[qd * 4 + 1]);
            acc[qd * 4 + 2] = fmaf(w, a.z, acc[qd * 4 + 2]);
            acc[qd * 4 + 3] = fmaf(w, a.w, acc[qd * 4 + 3]);
        }
    }

    // transpose through LDS for coalesced stores
#pragma unroll
    for (int n = 0; n < 32; ++n) tr[o * 33 + n] = fmaxf(0.f, acc[n]);
    __syncthreads();
    int n = threadIdx.x & 31, og = threadIdx.x >> 5;   // 8 channel groups
    float* ob = out + ((size_t)b * 384) * NPTS + nt + n;
#pragma unroll 4
    for (int c = 0; c < 32; ++c) {
        int ch = og * 32 + c;
        ob[(size_t)ch * NPTS] = tr[ch * 33 + n];
    }
}

extern "C" void kernel_launch(void* const* d_in, const int* in_sizes, int n_in,
                              void* d_out, int out_size, void* d_ws, size_t ws_size,
                              hipStream_t stream) {
    const float* X   = (const float*)d_in[0];
    const float* W1a = (const float*)d_in[1];
    const float* b1a = (const float*)d_in[2];
    const float* W2a = (const float*)d_in[3];
    const float* b2a = (const float*)d_in[4];
    const float* W1b = (const float*)d_in[5];
    const float* b1b = (const float*)d_in[6];
    const float* W2b = (const float*)d_in[7];
    const float* b2b = (const float*)d_in[8];
    const float* Wc1 = (const float*)d_in[9];
    const float* bc1 = (const float*)d_in[10];
    const float* Wc2 = (const float*)d_in[11];
    const float* bc2 = (const float*)d_in[12];
    float* out = (float*)d_out;

    // workspace layout (~20.1 MB)
    float* fa = (float*)d_ws;                         // 8*2048*64
    float* fb = fa + (size_t)NB * NPTS * 64;          // 8*2048*128
    float* v  = fb + (size_t)NB * NPTS * 128;         // 8*128*2048
    float* wT = v  + (size_t)NB * 128 * NPTS;         // 128*256

    k_features<<<NB * NPTS / 64, 512, 0, stream>>>(X, W1a, b1a, W2a, b2a,
                                                   W1b, b1b, W2b, b2b, Wc1, bc1,
                                                   Wc2, fa, fb, v, wT);
    k_neighbors<<<NB * NPTS / 16, 1024, 0, stream>>>(X, fa, fb, v, out);
    k_conv2<<<NB * (NPTS / 32), 256, 0, stream>>>(v, wT, bc2, out);
}

// Round 4
// 237.927 us; speedup vs baseline: 1.4387x; 1.0725x over previous
//
#include <hip/hip_runtime.h>
#include <cstdint>

#define NPTS 2048
#define NB 8
// float32 of (0.45*0.45 computed in float64) -- matches jnp/np scalar cast.
// NOTE: 0.45f*0.45f is 1 ulp LOWER; do not use it.
#define R2C 0.2025f

__device__ __forceinline__ float fmul(float a, float b) { return __fmul_rn(a, b); }
__device__ __forceinline__ float fadd(float a, float b) { return __fadd_rn(a, b); }

// ---------------- K0: Wc2 transpose (single block, one XCD/L2) ----------------
__global__ __launch_bounds__(256) void k_wt(const float* __restrict__ Wc2,
                                            float* __restrict__ wT) {
    for (int j = threadIdx.x; j < 256 * 128; j += 256) {
        int o = j >> 7, k = j & 127;
        wT[k * 256 + o] = Wc2[j];
    }
}

// ---------------- K1: per-point features ----------------
// 1024 threads = 16 waves; 64 points/block (same points in every wave);
// wave q computes channel slice q -> weight reads are wave-uniform s_loads,
// 4 waves/SIMD hide the SMEM latency.
__global__ __launch_bounds__(1024) void k_features(
    const float* __restrict__ X,
    const float* __restrict__ W1a, const float* __restrict__ b1a,
    const float* __restrict__ W2a, const float* __restrict__ b2a,
    const float* __restrict__ W1b, const float* __restrict__ b1b,
    const float* __restrict__ W2b, const float* __restrict__ b2b,
    const float* __restrict__ Wc1, const float* __restrict__ bc1,
    float* __restrict__ fa, float* __restrict__ fb, float* __restrict__ v)
{
    int tid = threadIdx.x;
    int q = __builtin_amdgcn_readfirstlane(tid >> 6);   // wave 0..15 (SGPR)
    int lane = tid & 63;
    int p = blockIdx.x * 64 + lane;                     // 0..16383
    int b = p >> 11, i = p & 2047;

    float x0 = X[p * 3 + 0], x1 = X[p * 3 + 1], x2 = X[p * 3 + 2];

    float h[64];
    // ---- branch a: h (32), then 4 channels (q*4..q*4+3) ----
#pragma unroll
    for (int o = 0; o < 32; ++o)
        h[o] = fmaxf(0.f, x0 * W1a[o * 3] + x1 * W1a[o * 3 + 1] + x2 * W1a[o * 3 + 2] + b1a[o]);
    float* fap = fa + (size_t)p * 64;
#pragma unroll
    for (int oo = 0; oo < 4; ++oo) {
        int o = q * 4 + oo;
        float acc = b2a[o];
#pragma unroll
        for (int k = 0; k < 32; ++k) acc = fmaf(h[k], W2a[o * 32 + k], acc);
        fap[o] = fmaxf(0.f, acc);
    }
    // ---- branch b: h (64), then 8 channels (q*8..q*8+7) ----
#pragma unroll
    for (int o = 0; o < 64; ++o)
        h[o] = fmaxf(0.f, x0 * W1b[o * 3] + x1 * W1b[o * 3 + 1] + x2 * W1b[o * 3 + 2] + b1b[o]);
    float* fbp = fb + (size_t)p * 128;
#pragma unroll
    for (int oo = 0; oo < 8; ++oo) {
        int o = q * 8 + oo;
        float acc = b2b[o];
#pragma unroll
        for (int k = 0; k < 64; ++k) acc = fmaf(h[k], W2b[o * 64 + k], acc);
        fbp[o] = fmaxf(0.f, acc);
    }
    // ---- conv1 path -> v channels q*4..q*4+3 (contiguous 256B stores) ----
    float* vb = v + (size_t)b * 128 * NPTS + i;
#pragma unroll
    for (int oo = 0; oo < 4; ++oo) {
        int o = q * 4 + oo;
        vb[(size_t)o * NPTS] =
            fmaxf(0.f, x0 * Wc1[o * 3] + x1 * Wc1[o * 3 + 1] + x2 * Wc1[o * 3 + 2] + bc1[o]);
    }
}

// ---------------- K2: ball query + neighborhood max-pool ----------------
// One wave per point; 16 waves/block; results staged in LDS tiles and
// stored cooperatively with full-cache-line coverage (no L2 merge reliance).
__global__ __launch_bounds__(1024) void k_neighbors(
    const float* __restrict__ X, const float* __restrict__ fa,
    const float* __restrict__ fb, float* __restrict__ v, float* __restrict__ out)
{
    __shared__ float xs[NPTS * 3];                // 24KB (AoS, stride-3 reads)
    __shared__ unsigned short nbr[16][128];       // 4KB
    __shared__ float g1t[64][17];                 // 4.25KB [ch][pt]
    __shared__ float g2t[128][17];                // 8.5KB  [ch][pt]
    int tid = threadIdx.x;
    int wid = tid >> 6, lane = tid & 63;
    int b = blockIdx.x & 7;                       // batch-per-XCD L2 affinity
    int i0 = (blockIdx.x >> 3) * 16;
    int i = i0 + wid;                             // this wave's point

    // stage x[b] (24KB), float4-coalesced
    const float4* xsrc = (const float4*)(X + (size_t)b * NPTS * 3);
    float4* xdst = (float4*)xs;
    for (int t = tid; t < (NPTS * 3 / 4); t += 1024) xdst[t] = xsrc[t];
    __syncthreads();

    float n0 = xs[i * 3], n1 = xs[i * 3 + 1], n2 = xs[i * 3 + 2];
    float nn = fadd(fadd(fmul(n0, n0), fmul(n1, n1)), fmul(n2, n2));

    // 32 ballot words; lane w keeps word w (exact numpy arithmetic, no FMA)
    unsigned long long myword = 0;
    for (int w = 0; w < 32; ++w) {
        int m = (w << 6) | lane;
        float y0 = xs[m * 3], y1 = xs[m * 3 + 1], y2 = xs[m * 3 + 2];
        float dot = fadd(fadd(fmul(n0, y0), fmul(n1, y1)), fmul(n2, y2));
        float mm  = fadd(fadd(fmul(y0, y0), fmul(y1, y1)), fmul(y2, y2));
        float d   = fadd(fadd(fmul(-2.0f, dot), nn), mm);
        unsigned long long bm = __ballot(!(d > R2C));
        if (lane == w) myword = bm;
    }

    // parallel decode: prefix-sum of per-word popcounts -> rank base
    int cnt = (lane < 32) ? __popcll(myword) : 0;
    int incl = cnt;
#pragma unroll
    for (int d = 1; d < 32; d <<= 1) {
        int t = __shfl_up(incl, d, 64);
        if (lane >= d) incl += t;
    }
    int pre = incl - cnt;
    if (lane < 32 && cnt && pre < 128) {
        unsigned long long word = myword;
        int r = pre;
        while (word && r < 128) {
            int pb = __builtin_ctzll(word);
            word &= word - 1;
            nbr[wid][r++] = (unsigned short)((lane << 6) | pb);
        }
    }
    int total = __shfl(incl, 31, 64);
    int c1 = min(total, 64);
    int c2 = min(total, 128);
    __syncthreads();

    // ---- pool 1: first 64 -> max of fa (lane = channel) ----
    {
        const float* fab = fa + (size_t)b * NPTS * 64 + lane;
        float g1 = -1e30f;
        int j = 0;
        for (; j + 8 <= c1; j += 8) {
            ushort4 qa = *(const ushort4*)&nbr[wid][j];
            ushort4 qb = *(const ushort4*)&nbr[wid][j + 4];
            float a0 = fab[(size_t)qa.x * 64];
            float a1 = fab[(size_t)qa.y * 64];
            float a2 = fab[(size_t)qa.z * 64];
            float a3 = fab[(size_t)qa.w * 64];
            float a4 = fab[(size_t)qb.x * 64];
            float a5 = fab[(size_t)qb.y * 64];
            float a6 = fab[(size_t)qb.z * 64];
            float a7 = fab[(size_t)qb.w * 64];
            g1 = fmaxf(g1, fmaxf(fmaxf(fmaxf(a0, a1), fmaxf(a2, a3)),
                                 fmaxf(fmaxf(a4, a5), fmaxf(a6, a7))));
        }
        for (; j < c1; ++j) g1 = fmaxf(g1, fab[(size_t)nbr[wid][j] * 64]);
        g1t[lane][wid] = g1;
    }
    // ---- pool 2: first 128 -> max of fb (lane = channel pair) ----
    {
        const float2* fbb = (const float2*)(fb + (size_t)b * NPTS * 128) + lane;
        float2 g2; g2.x = -1e30f; g2.y = -1e30f;
        int j = 0;
        for (; j + 8 <= c2; j += 8) {
            ushort4 qa = *(const ushort4*)&nbr[wid][j];
            ushort4 qb = *(const ushort4*)&nbr[wid][j + 4];
            float2 a0 = fbb[(size_t)qa.x * 64];
            float2 a1 = fbb[(size_t)qa.y * 64];
            float2 a2 = fbb[(size_t)qa.z * 64];
            float2 a3 = fbb[(size_t)qa.w * 64];
            float2 a4 = fbb[(size_t)qb.x * 64];
            float2 a5 = fbb[(size_t)qb.y * 64];
            float2 a6 = fbb[(size_t)qb.z * 64];
            float2 a7 = fbb[(size_t)qb.w * 64];
            g2.x = fmaxf(g2.x, fmaxf(fmaxf(fmaxf(a0.x, a1.x), fmaxf(a2.x, a3.x)),
                                     fmaxf(fmaxf(a4.x, a5.x), fmaxf(a6.x, a7.x))));
            g2.y = fmaxf(g2.y, fmaxf(fmaxf(fmaxf(a0.y, a1.y), fmaxf(a2.y, a3.y)),
                                     fmaxf(fmaxf(a4.y, a5.y), fmaxf(a6.y, a7.y))));
        }
        for (; j < c2; ++j) {
            float2 a = fbb[(size_t)nbr[wid][j] * 64];
            g2.x = fmaxf(g2.x, a.x); g2.y = fmaxf(g2.y, a.y);
        }
        g2t[2 * lane][wid] = g2.x;
        g2t[2 * lane + 1][wid] = g2.y;
    }
    __syncthreads();

    // ---- cooperative coalesced stores (full 64B lines per 16-lane group) ----
    {
        int ch = tid >> 4, pt = tid & 15;         // 64 ch x 16 pts
        v[((size_t)b * 128 + 64 + ch) * NPTS + i0 + pt] = g1t[ch][pt];
    }
#pragma unroll
    for (int r = 0; r < 2; ++r) {
        int idx = r * 1024 + tid;
        int ch = idx >> 4, pt = idx & 15;         // 128 ch x 16 pts
        out[((size_t)b * 384 + 256 + ch) * NPTS + i0 + pt] = g2t[ch][pt];
    }
}

// ---------------- K3: 256x128 pointwise conv (register-tiled GEMM) ----------------
// Block tile: O=256, N=32. Thread owns 4 ch x 8 pts (32 acc).
// Per k-step: 3 LDS reads per 32 FMAs -> VALU-bound.
__global__ __launch_bounds__(256) void k_conv2(
    const float* __restrict__ v, const float* __restrict__ wT,
    const float* __restrict__ bc2, float* __restrict__ out)
{
    __shared__ float vs[128 * 32];    // 16KB [k][n]
    __shared__ float ws[32 * 256];    // 32KB [kk][o] chunk
    int b = blockIdx.x & 7;           // batch-per-XCD affinity
    int nt = (blockIdx.x >> 3) << 5;  // 32-point tile
    int t = threadIdx.x;
    int n_t = t & 3, o_t = t >> 2;    // n_t: 8-pt group, o_t: 4-ch group (0..63)

    // stage v tile (coalesced 128B rows)
    const float* vb = v + (size_t)b * 128 * NPTS + nt;
#pragma unroll
    for (int r = 0; r < 4; ++r) {
        int j = r * 256 + t; int k = j >> 3, n4 = j & 7;
        *(float4*)&vs[k * 32 + n4 * 4] = *(const float4*)(vb + (size_t)k * NPTS + n4 * 4);
    }

    float4 bias = *(const float4*)(bc2 + o_t * 4);
    float acc[4][8];
#pragma unroll
    for (int r = 0; r < 4; ++r)
#pragma unroll
        for (int n = 0; n < 8; ++n) acc[r][n] = ((const float*)&bias)[r];

    for (int kc = 0; kc < 128; kc += 32) {
        __syncthreads();
        // stage wT chunk [32][256] (coalesced 1KB rows)
#pragma unroll
        for (int r = 0; r < 8; ++r) {
            int j = r * 256 + t; int kk = j >> 6, o4 = j & 63;
            *(float4*)&ws[kk * 256 + o4 * 4] =
                *(const float4*)(wT + (size_t)(kc + kk) * 256 + o4 * 4);
        }
        __syncthreads();
#pragma unroll 4
        for (int kk = 0; kk < 32; ++kk) {
            float4 w = *(float4*)&ws[kk * 256 + o_t * 4];
            float4 va = *(float4*)&vs[(kc + kk) * 32 + n_t * 8];
            float4 vb4 = *(float4*)&vs[(kc + kk) * 32 + n_t * 8 + 4];
            float vv[8] = {va.x, va.y, va.z, va.w, vb4.x, vb4.y, vb4.z, vb4.w};
            float ww[4] = {w.x, w.y, w.z, w.w};
#pragma unroll
            for (int r = 0; r < 4; ++r)
#pragma unroll
                for (int n = 0; n < 8; ++n)
                    acc[r][n] = fmaf(ww[r], vv[n], acc[r][n]);
        }
    }

    // stores: per instr, 4-lane groups write 32 consecutive floats (full lines)
    float* ob = out + ((size_t)b * 384 + o_t * 4) * NPTS + nt + n_t * 8;
#pragma unroll
    for (int r = 0; r < 4; ++r) {
        float4 s0, s1;
        s0.x = fmaxf(0.f, acc[r][0]); s0.y = fmaxf(0.f, acc[r][1]);
        s0.z = fmaxf(0.f, acc[r][2]); s0.w = fmaxf(0.f, acc[r][3]);
        s1.x = fmaxf(0.f, acc[r][4]); s1.y = fmaxf(0.f, acc[r][5]);
        s1.z = fmaxf(0.f, acc[r][6]); s1.w = fmaxf(0.f, acc[r][7]);
        *(float4*)(ob + (size_t)r * NPTS) = s0;
        *(float4*)(ob + (size_t)r * NPTS + 4) = s1;
    }
}

extern "C" void kernel_launch(void* const* d_in, const int* in_sizes, int n_in,
                              void* d_out, int out_size, void* d_ws, size_t ws_size,
                              hipStream_t stream) {
    const float* X   = (const float*)d_in[0];
    const float* W1a = (const float*)d_in[1];
    const float* b1a = (const float*)d_in[2];
    const float* W2a = (const float*)d_in[3];
    const float* b2a = (const float*)d_in[4];
    const float* W1b = (const float*)d_in[5];
    const float* b1b = (const float*)d_in[6];
    const float* W2b = (const float*)d_in[7];
    const float* b2b = (const float*)d_in[8];
    const float* Wc1 = (const float*)d_in[9];
    const float* bc1 = (const float*)d_in[10];
    const float* Wc2 = (const float*)d_in[11];
    const float* bc2 = (const float*)d_in[12];
    float* out = (float*)d_out;

    // workspace layout (~20.1 MB)
    float* fa = (float*)d_ws;                         // 8*2048*64
    float* fb = fa + (size_t)NB * NPTS * 64;          // 8*2048*128
    float* v  = fb + (size_t)NB * NPTS * 128;         // 8*128*2048
    float* wT = v  + (size_t)NB * 128 * NPTS;         // 128*256

    k_wt<<<1, 256, 0, stream>>>(Wc2, wT);
    k_features<<<NB * NPTS / 64, 1024, 0, stream>>>(X, W1a, b1a, W2a, b2a,
                                                    W1b, b1b, W2b, b2b, Wc1, bc1,
                                                    fa, fb, v);
    k_neighbors<<<NB * NPTS / 16, 1024, 0, stream>>>(X, fa, fb, v, out);
    k_conv2<<<NB * (NPTS / 32), 256, 0, stream>>>(v, wT, bc2, out);
}

// Round 5
// 205.785 us; speedup vs baseline: 1.6634x; 1.1562x over previous
//
#include <hip/hip_runtime.h>
#include <cstdint>

#define NPTS 2048
#define NB 8
// float32 of (0.45*0.45 computed in float64) -- matches jnp/np scalar cast.
// NOTE: 0.45f*0.45f is 1 ulp LOWER; do not use it.
#define R2C 0.2025f

__device__ __forceinline__ float fmul(float a, float b) { return __fmul_rn(a, b); }
__device__ __forceinline__ float fadd(float a, float b) { return __fadd_rn(a, b); }

// ---------------- K1: per-point features ----------------
// 1024 threads = 16 waves; 64 points/block; wave q computes channel slice q
// (weight reads wave-uniform -> s_load). Results staged in padded LDS tiles,
// then stored cooperatively as contiguous full-line runs (no 64-line scatter).
__global__ __launch_bounds__(1024) void k_features(
    const float* __restrict__ X,
    const float* __restrict__ W1a, const float* __restrict__ b1a,
    const float* __restrict__ W2a, const float* __restrict__ b2a,
    const float* __restrict__ W1b, const float* __restrict__ b1b,
    const float* __restrict__ W2b, const float* __restrict__ b2b,
    const float* __restrict__ Wc1, const float* __restrict__ bc1,
    float* __restrict__ fa, float* __restrict__ fb, float* __restrict__ v)
{
    __shared__ float fat[64][65];    // 16.6KB, bank-free both access patterns
    __shared__ float fbt[64][129];   // 33.0KB
    int tid = threadIdx.x;
    int q = __builtin_amdgcn_readfirstlane(tid >> 6);   // wave 0..15 (SGPR)
    int lane = tid & 63;
    int pbase = blockIdx.x * 64;
    int p = pbase + lane;                               // 0..16383
    int b = p >> 11, i = p & 2047;

    float x0 = X[p * 3 + 0], x1 = X[p * 3 + 1], x2 = X[p * 3 + 2];

    float h[64];
    // ---- branch a: h (32), then 4 channels (q*4..q*4+3) ----
#pragma unroll
    for (int o = 0; o < 32; ++o)
        h[o] = fmaxf(0.f, x0 * W1a[o * 3] + x1 * W1a[o * 3 + 1] + x2 * W1a[o * 3 + 2] + b1a[o]);
#pragma unroll
    for (int oo = 0; oo < 4; ++oo) {
        int o = q * 4 + oo;
        float acc = b2a[o];
#pragma unroll
        for (int k = 0; k < 32; ++k) acc = fmaf(h[k], W2a[o * 32 + k], acc);
        fat[lane][o] = fmaxf(0.f, acc);
    }
    // ---- branch b: h (64), then 8 channels (q*8..q*8+7) ----
#pragma unroll
    for (int o = 0; o < 64; ++o)
        h[o] = fmaxf(0.f, x0 * W1b[o * 3] + x1 * W1b[o * 3 + 1] + x2 * W1b[o * 3 + 2] + b1b[o]);
#pragma unroll
    for (int oo = 0; oo < 8; ++oo) {
        int o = q * 8 + oo;
        float acc = b2b[o];
#pragma unroll
        for (int k = 0; k < 64; ++k) acc = fmaf(h[k], W2b[o * 64 + k], acc);
        fbt[lane][o] = fmaxf(0.f, acc);
    }
    // ---- conv1 path -> v channels q*4..q*4+3 (lane=i: coalesced rows) ----
    float* vb = v + (size_t)b * 128 * NPTS + i;
#pragma unroll
    for (int oo = 0; oo < 4; ++oo) {
        int o = q * 4 + oo;
        vb[(size_t)o * NPTS] =
            fmaxf(0.f, x0 * Wc1[o * 3] + x1 * Wc1[o * 3 + 1] + x2 * Wc1[o * 3 + 2] + bc1[o]);
    }
    __syncthreads();

    // cooperative coalesced stores: fa rows contiguous (16KB run), fb (32KB run)
#pragma unroll
    for (int r = 0; r < 4; ++r) {
        int idx = r * 1024 + tid;
        int pt = idx >> 6, ch = idx & 63;
        fa[((size_t)(pbase + pt)) * 64 + ch] = fat[pt][ch];
    }
#pragma unroll
    for (int r = 0; r < 8; ++r) {
        int idx = r * 1024 + tid;
        int pt = idx >> 7, ch = idx & 127;
        fb[((size_t)(pbase + pt)) * 128 + ch] = fbt[pt][ch];
    }
}

// ---------------- K2: ball query + neighborhood max-pool ----------------
// One wave per point; 16 waves/block; results staged in LDS tiles and
// stored cooperatively with full-cache-line coverage. (Unchanged from R4.)
__global__ __launch_bounds__(1024) void k_neighbors(
    const float* __restrict__ X, const float* __restrict__ fa,
    const float* __restrict__ fb, float* __restrict__ v, float* __restrict__ out)
{
    __shared__ float xs[NPTS * 3];                // 24KB
    __shared__ unsigned short nbr[16][128];       // 4KB
    __shared__ float g1t[64][17];                 // 4.25KB [ch][pt]
    __shared__ float g2t[128][17];                // 8.5KB  [ch][pt]
    int tid = threadIdx.x;
    int wid = tid >> 6, lane = tid & 63;
    int b = blockIdx.x & 7;                       // batch-per-XCD L2 affinity
    int i0 = (blockIdx.x >> 3) * 16;
    int i = i0 + wid;                             // this wave's point

    const float4* xsrc = (const float4*)(X + (size_t)b * NPTS * 3);
    float4* xdst = (float4*)xs;
    for (int t = tid; t < (NPTS * 3 / 4); t += 1024) xdst[t] = xsrc[t];
    __syncthreads();

    float n0 = xs[i * 3], n1 = xs[i * 3 + 1], n2 = xs[i * 3 + 2];
    float nn = fadd(fadd(fmul(n0, n0), fmul(n1, n1)), fmul(n2, n2));

    unsigned long long myword = 0;
    for (int w = 0; w < 32; ++w) {
        int m = (w << 6) | lane;
        float y0 = xs[m * 3], y1 = xs[m * 3 + 1], y2 = xs[m * 3 + 2];
        float dot = fadd(fadd(fmul(n0, y0), fmul(n1, y1)), fmul(n2, y2));
        float mm  = fadd(fadd(fmul(y0, y0), fmul(y1, y1)), fmul(y2, y2));
        float d   = fadd(fadd(fmul(-2.0f, dot), nn), mm);
        unsigned long long bm = __ballot(!(d > R2C));
        if (lane == w) myword = bm;
    }

    int cnt = (lane < 32) ? __popcll(myword) : 0;
    int incl = cnt;
#pragma unroll
    for (int d = 1; d < 32; d <<= 1) {
        int t = __shfl_up(incl, d, 64);
        if (lane >= d) incl += t;
    }
    int pre = incl - cnt;
    if (lane < 32 && cnt && pre < 128) {
        unsigned long long word = myword;
        int r = pre;
        while (word && r < 128) {
            int pb = __builtin_ctzll(word);
            word &= word - 1;
            nbr[wid][r++] = (unsigned short)((lane << 6) | pb);
        }
    }
    int total = __shfl(incl, 31, 64);
    int c1 = min(total, 64);
    int c2 = min(total, 128);
    __syncthreads();

    {
        const float* fab = fa + (size_t)b * NPTS * 64 + lane;
        float g1 = -1e30f;
        int j = 0;
        for (; j + 8 <= c1; j += 8) {
            ushort4 qa = *(const ushort4*)&nbr[wid][j];
            ushort4 qb = *(const ushort4*)&nbr[wid][j + 4];
            float a0 = fab[(size_t)qa.x * 64];
            float a1 = fab[(size_t)qa.y * 64];
            float a2 = fab[(size_t)qa.z * 64];
            float a3 = fab[(size_t)qa.w * 64];
            float a4 = fab[(size_t)qb.x * 64];
            float a5 = fab[(size_t)qb.y * 64];
            float a6 = fab[(size_t)qb.z * 64];
            float a7 = fab[(size_t)qb.w * 64];
            g1 = fmaxf(g1, fmaxf(fmaxf(fmaxf(a0, a1), fmaxf(a2, a3)),
                                 fmaxf(fmaxf(a4, a5), fmaxf(a6, a7))));
        }
        for (; j < c1; ++j) g1 = fmaxf(g1, fab[(size_t)nbr[wid][j] * 64]);
        g1t[lane][wid] = g1;
    }
    {
        const float2* fbb = (const float2*)(fb + (size_t)b * NPTS * 128) + lane;
        float2 g2; g2.x = -1e30f; g2.y = -1e30f;
        int j = 0;
        for (; j + 8 <= c2; j += 8) {
            ushort4 qa = *(const ushort4*)&nbr[wid][j];
            ushort4 qb = *(const ushort4*)&nbr[wid][j + 4];
            float2 a0 = fbb[(size_t)qa.x * 64];
            float2 a1 = fbb[(size_t)qa.y * 64];
            float2 a2 = fbb[(size_t)qa.z * 64];
            float2 a3 = fbb[(size_t)qa.w * 64];
            float2 a4 = fbb[(size_t)qb.x * 64];
            float2 a5 = fbb[(size_t)qb.y * 64];
            float2 a6 = fbb[(size_t)qb.z * 64];
            float2 a7 = fbb[(size_t)qb.w * 64];
            g2.x = fmaxf(g2.x, fmaxf(fmaxf(fmaxf(a0.x, a1.x), fmaxf(a2.x, a3.x)),
                                     fmaxf(fmaxf(a4.x, a5.x), fmaxf(a6.x, a7.x))));
            g2.y = fmaxf(g2.y, fmaxf(fmaxf(fmaxf(a0.y, a1.y), fmaxf(a2.y, a3.y)),
                                     fmaxf(fmaxf(a4.y, a5.y), fmaxf(a6.y, a7.y))));
        }
        for (; j < c2; ++j) {
            float2 a = fbb[(size_t)nbr[wid][j] * 64];
            g2.x = fmaxf(g2.x, a.x); g2.y = fmaxf(g2.y, a.y);
        }
        g2t[2 * lane][wid] = g2.x;
        g2t[2 * lane + 1][wid] = g2.y;
    }
    __syncthreads();

    {
        int ch = tid >> 4, pt = tid & 15;
        v[((size_t)b * 128 + 64 + ch) * NPTS + i0 + pt] = g1t[ch][pt];
    }
#pragma unroll
    for (int r = 0; r < 2; ++r) {
        int idx = r * 1024 + tid;
        int ch = idx >> 4, pt = idx & 15;
        out[((size_t)b * 384 + 256 + ch) * NPTS + i0 + pt] = g2t[ch][pt];
    }
}

// ---------------- K3: 256x128 pointwise conv (register-tiled GEMM) ----------------
// Block tile: O=256, N=32, K chunked by 32. Thread owns 4 ch x 8 pts.
// Wc2 staged straight from row-major into padded LDS (no separate transpose kernel).
__global__ __launch_bounds__(256) void k_conv2(
    const float* __restrict__ v, const float* __restrict__ Wc2,
    const float* __restrict__ bc2, float* __restrict__ out)
{
    __shared__ float vs[128 * 32];    // 16KB [k][n]
    __shared__ float ws[256 * 33];    // 33KB [o][kk-chunk], +1 pad
    int b = blockIdx.x & 7;           // batch-per-XCD affinity
    int nt = (blockIdx.x >> 3) << 5;  // 32-point tile
    int t = threadIdx.x;
    int n_t = t & 3, o_t = t >> 2;    // n_t: 8-pt group, o_t: 4-ch group (0..63)

    // stage v tile (coalesced 128B segments)
    const float* vb = v + (size_t)b * 128 * NPTS + nt;
#pragma unroll
    for (int r = 0; r < 4; ++r) {
        int j = r * 256 + t; int k = j >> 3, n4 = j & 7;
        *(float4*)&vs[k * 32 + n4 * 4] = *(const float4*)(vb + (size_t)k * NPTS + n4 * 4);
    }

    float acc[4][8];
#pragma unroll
    for (int r = 0; r < 4; ++r) {
        float bb = bc2[o_t * 4 + r];
#pragma unroll
        for (int n = 0; n < 8; ++n) acc[r][n] = bb;
    }

    for (int kc = 0; kc < 128; kc += 32) {
        __syncthreads();               // prev chunk's reads done (also fences vs)
        // stage Wc2[:, kc..kc+31]: coalesced row-segment reads, scalar ds_writes
#pragma unroll
        for (int r = 0; r < 8; ++r) {
            int j = r * 256 + t; int o = j >> 3, c = j & 7;
            float4 wv = *(const float4*)(Wc2 + (size_t)o * 128 + kc + c * 4);
            ws[o * 33 + c * 4 + 0] = wv.x;
            ws[o * 33 + c * 4 + 1] = wv.y;
            ws[o * 33 + c * 4 + 2] = wv.z;
            ws[o * 33 + c * 4 + 3] = wv.w;
        }
        __syncthreads();
#pragma unroll 4
        for (int kk = 0; kk < 32; ++kk) {
            float4 va = *(float4*)&vs[(kc + kk) * 32 + n_t * 8];
            float4 vb4 = *(float4*)&vs[(kc + kk) * 32 + n_t * 8 + 4];
            float vv[8] = {va.x, va.y, va.z, va.w, vb4.x, vb4.y, vb4.z, vb4.w};
            float ww[4];
#pragma unroll
            for (int r = 0; r < 4; ++r) ww[r] = ws[(o_t * 4 + r) * 33 + kk];
#pragma unroll
            for (int r = 0; r < 4; ++r)
#pragma unroll
                for (int n = 0; n < 8; ++n)
                    acc[r][n] = fmaf(ww[r], vv[n], acc[r][n]);
        }
    }

    // stores: 4-lane groups cover 32 consecutive floats (full lines)
    float* ob = out + ((size_t)b * 384 + o_t * 4) * NPTS + nt + n_t * 8;
#pragma unroll
    for (int r = 0; r < 4; ++r) {
        float4 s0, s1;
        s0.x = fmaxf(0.f, acc[r][0]); s0.y = fmaxf(0.f, acc[r][1]);
        s0.z = fmaxf(0.f, acc[r][2]); s0.w = fmaxf(0.f, acc[r][3]);
        s1.x = fmaxf(0.f, acc[r][4]); s1.y = fmaxf(0.f, acc[r][5]);
        s1.z = fmaxf(0.f, acc[r][6]); s1.w = fmaxf(0.f, acc[r][7]);
        *(float4*)(ob + (size_t)r * NPTS) = s0;
        *(float4*)(ob + (size_t)r * NPTS + 4) = s1;
    }
}

extern "C" void kernel_launch(void* const* d_in, const int* in_sizes, int n_in,
                              void* d_out, int out_size, void* d_ws, size_t ws_size,
                              hipStream_t stream) {
    const float* X   = (const float*)d_in[0];
    const float* W1a = (const float*)d_in[1];
    const float* b1a = (const float*)d_in[2];
    const float* W2a = (const float*)d_in[3];
    const float* b2a = (const float*)d_in[4];
    const float* W1b = (const float*)d_in[5];
    const float* b1b = (const float*)d_in[6];
    const float* W2b = (const float*)d_in[7];
    const float* b2b = (const float*)d_in[8];
    const float* Wc1 = (const float*)d_in[9];
    const float* bc1 = (const float*)d_in[10];
    const float* Wc2 = (const float*)d_in[11];
    const float* bc2 = (const float*)d_in[12];
    float* out = (float*)d_out;

    // workspace layout (~20 MB)
    float* fa = (float*)d_ws;                         // 8*2048*64
    float* fb = fa + (size_t)NB * NPTS * 64;          // 8*2048*128
    float* v  = fb + (size_t)NB * NPTS * 128;         // 8*128*2048

    k_features<<<NB * NPTS / 64, 1024, 0, stream>>>(X, W1a, b1a, W2a, b2a,
                                                    W1b, b1b, W2b, b2b, Wc1, bc1,
                                                    fa, fb, v);
    k_neighbors<<<NB * NPTS / 16, 1024, 0, stream>>>(X, fa, fb, v, out);
    k_conv2<<<NB * (NPTS / 32), 256, 0, stream>>>(v, Wc2, bc2, out);
}

// Round 7
// 194.018 us; speedup vs baseline: 1.7643x; 1.0606x over previous
//
#include <hip/hip_runtime.h>
#include <hip/hip_fp16.h>
#include <cstdint>

#define NPTS 2048
#define NB 8
// float32 of (0.45*0.45 computed in float64) -- matches jnp/np scalar cast.
// NOTE: 0.45f*0.45f is 1 ulp LOWER; do not use it.
#define R2C 0.2025f

__device__ __forceinline__ float fmul(float a, float b) { return __fmul_rn(a, b); }
__device__ __forceinline__ float fadd(float a, float b) { return __fadd_rn(a, b); }

// packed fp16 max (header lacks __hmax2 on gfx950; ISA has v_pk_max_f16)
__device__ __forceinline__ uint hmax2u(uint a, uint b) {
    uint r;
    asm volatile("v_pk_max_f16 %0, %1, %2" : "=v"(r) : "v"(a), "v"(b));
    return r;
}
__device__ __forceinline__ float lo_f(uint u) {
    __half h = __ushort_as_half((unsigned short)(u & 0xffff));
    return __half2float(h);
}
__device__ __forceinline__ float hi_f(uint u) {
    __half h = __ushort_as_half((unsigned short)(u >> 16));
    return __half2float(h);
}

// ---------------- K1: per-point features ----------------
// 512 threads = 8 waves; 64 points/block; wave q computes channel slice q
// (weight reads wave-uniform -> s_load). launch_bounds(512,4): VGPR cap 128,
// h[64] fits WITHOUT scratch spill (1024-thread version capped at 64 VGPR and
// spilled -- that was the hidden ~50us). fa/fb stored as fp16 pairs via
// padded LDS tiles + cooperative contiguous dword stores.
__global__ __launch_bounds__(512, 4) void k_features(
    const float* __restrict__ X,
    const float* __restrict__ W1a, const float* __restrict__ b1a,
    const float* __restrict__ W2a, const float* __restrict__ b2a,
    const float* __restrict__ W1b, const float* __restrict__ b1b,
    const float* __restrict__ W2b, const float* __restrict__ b2b,
    const float* __restrict__ Wc1, const float* __restrict__ bc1,
    __half* __restrict__ fa, __half* __restrict__ fb, float* __restrict__ v)
{
    __shared__ float fat[64 * 33];   // 64 pts x 32 dwords (64 half ch), pad 33
    __shared__ float fbt[64 * 67];   // 64 pts x 64 dwords (128 half ch), pad 67
    int tid = threadIdx.x;
    int q = __builtin_amdgcn_readfirstlane(tid >> 6);   // wave 0..7 (SGPR)
    int lane = tid & 63;
    int pbase = blockIdx.x * 64;
    int p = pbase + lane;
    int b = p >> 11, i = p & 2047;

    float x0 = X[p * 3 + 0], x1 = X[p * 3 + 1], x2 = X[p * 3 + 2];

    float h[64];
    // ---- branch a: h (32), then 8 channels (q*8..q*8+7) as 4 half2 ----
#pragma unroll
    for (int o = 0; o < 32; ++o)
        h[o] = fmaxf(0.f, x0 * W1a[o * 3] + x1 * W1a[o * 3 + 1] + x2 * W1a[o * 3 + 2] + b1a[o]);
#pragma unroll
    for (int oo = 0; oo < 8; oo += 2) {
        int o = q * 8 + oo;
        float a0 = b2a[o], a1 = b2a[o + 1];
#pragma unroll
        for (int k = 0; k < 32; ++k) {
            a0 = fmaf(h[k], W2a[o * 32 + k], a0);
            a1 = fmaf(h[k], W2a[(o + 1) * 32 + k], a1);
        }
        __half2 hh = __floats2half2_rn(fmaxf(0.f, a0), fmaxf(0.f, a1));
        fat[lane * 33 + q * 4 + (oo >> 1)] = *(float*)&hh;
    }
    // ---- branch b: h (64), then 16 channels (q*16..q*16+15) as 8 half2 ----
#pragma unroll
    for (int o = 0; o < 64; ++o)
        h[o] = fmaxf(0.f, x0 * W1b[o * 3] + x1 * W1b[o * 3 + 1] + x2 * W1b[o * 3 + 2] + b1b[o]);
#pragma unroll
    for (int oo = 0; oo < 16; oo += 2) {
        int o = q * 16 + oo;
        float a0 = b2b[o], a1 = b2b[o + 1];
#pragma unroll
        for (int k = 0; k < 64; ++k) {
            a0 = fmaf(h[k], W2b[o * 64 + k], a0);
            a1 = fmaf(h[k], W2b[(o + 1) * 64 + k], a1);
        }
        __half2 hh = __floats2half2_rn(fmaxf(0.f, a0), fmaxf(0.f, a1));
        fbt[lane * 67 + q * 8 + (oo >> 1)] = *(float*)&hh;
    }
    // ---- conv1 path -> v channels q*8..q*8+7 (lane=i: coalesced rows, f32) ----
    float* vb = v + (size_t)b * 128 * NPTS + i;
#pragma unroll
    for (int oo = 0; oo < 8; ++oo) {
        int o = q * 8 + oo;
        vb[(size_t)o * NPTS] =
            fmaxf(0.f, x0 * Wc1[o * 3] + x1 * Wc1[o * 3 + 1] + x2 * Wc1[o * 3 + 2] + bc1[o]);
    }
    __syncthreads();

    // cooperative contiguous dword stores
    uint* fau = (uint*)fa;
#pragma unroll
    for (int r = 0; r < 4; ++r) {
        int idx = r * 512 + tid;                 // 2048 dwords
        int pt = idx >> 5, j = idx & 31;
        fau[((size_t)(pbase + pt)) * 32 + j] = *(uint*)&fat[pt * 33 + j];
    }
    uint* fbu = (uint*)fb;
#pragma unroll
    for (int r = 0; r < 8; ++r) {
        int idx = r * 512 + tid;                 // 4096 dwords
        int pt = idx >> 6, j = idx & 63;
        fbu[((size_t)(pbase + pt)) * 64 + j] = *(uint*)&fbt[pt * 67 + j];
    }
}

// ---------------- K2: ball query + neighborhood max-pool (fp16 features) ----------------
// One wave per point; 16 waves/block. Multi-row vector loads: one dwordx4
// covers 8 fa-rows / 4 fb-rows (lane-group = row). Tail handled by clamping
// the row index to c-1 (duplicate neighbor, max-invariant). Features are
// ReLU outputs (>=0) so packed-zero init is a valid max identity.
__global__ __launch_bounds__(1024) void k_neighbors(
    const float* __restrict__ X, const __half* __restrict__ fa,
    const __half* __restrict__ fb, float* __restrict__ v, float* __restrict__ out)
{
    __shared__ float4 xs4[NPTS];                  // 32KB {x,y,z,|y|^2}
    __shared__ unsigned short nbr[16][128];       // 4KB
    __shared__ float g1t[64][17];                 // [ch][pt]
    __shared__ float g2t[128][17];                // [ch][pt]
    int tid = threadIdx.x;
    int wid = tid >> 6, lane = tid & 63;
    int b = blockIdx.x & 7;                       // batch-per-XCD L2 affinity
    int i0 = (blockIdx.x >> 3) * 16;
    int i = i0 + wid;                             // this wave's point

    const float* Xb = X + (size_t)b * NPTS * 3;
    for (int t = tid; t < NPTS; t += 1024) {
        float y0 = Xb[3 * t], y1 = Xb[3 * t + 1], y2 = Xb[3 * t + 2];
        float mm = fadd(fadd(fmul(y0, y0), fmul(y1, y1)), fmul(y2, y2));
        xs4[t] = make_float4(y0, y1, y2, mm);
    }
    __syncthreads();

    float4 cc = xs4[i];
    float n0 = cc.x, n1 = cc.y, n2 = cc.z, nn = cc.w;

    // 32 ballot words; lane w keeps word w (exact numpy arithmetic, no FMA)
    unsigned long long myword = 0;
    for (int w = 0; w < 32; ++w) {
        float4 y = xs4[(w << 6) | lane];
        float dot = fadd(fadd(fmul(n0, y.x), fmul(n1, y.y)), fmul(n2, y.z));
        float d   = fadd(fadd(fmul(-2.0f, dot), nn), y.w);
        unsigned long long bm = __ballot(!(d > R2C));
        if (lane == w) myword = bm;
    }

    // parallel decode: prefix-sum of per-word popcounts -> rank base
    int cnt = (lane < 32) ? __popcll(myword) : 0;
    int incl = cnt;
#pragma unroll
    for (int d = 1; d < 32; d <<= 1) {
        int t = __shfl_up(incl, d, 64);
        if (lane >= d) incl += t;
    }
    int pre = incl - cnt;
    if (lane < 32 && cnt && pre < 128) {
        unsigned long long word = myword;
        int r = pre;
        while (word && r < 128) {
            int pb = __builtin_ctzll(word);
            word &= word - 1;
            nbr[wid][r++] = (unsigned short)((lane << 6) | pb);
        }
    }
    int total = __shfl(incl, 31, 64);
    int c1 = min(total, 64);     // >=1 (self always in radius)
    int c2 = min(total, 128);
    __syncthreads();

    // ---- pool 1: first 64 -> max of fa. 8 rows per dwordx4 instr ----
    {
        const uint4* fab = (const uint4*)(fa + (size_t)b * NPTS * 64);
        int g = lane >> 3, c8 = lane & 7;         // row-in-group, channel-octet
        uint acc0 = 0, acc1 = 0, acc2 = 0, acc3 = 0;   // relu outputs >= 0
        int it1 = (c1 + 7) >> 3;
        for (int j = 0; j < it1; ++j) {
            int idx = min(j * 8 + g, c1 - 1);
            int row = nbr[wid][idx];
            uint4 rr = fab[row * 8 + c8];
            acc0 = hmax2u(acc0, rr.x);
            acc1 = hmax2u(acc1, rr.y);
            acc2 = hmax2u(acc2, rr.z);
            acc3 = hmax2u(acc3, rr.w);
        }
#pragma unroll
        for (int s = 8; s < 64; s <<= 1) {
            acc0 = hmax2u(acc0, (uint)__shfl_xor((int)acc0, s, 64));
            acc1 = hmax2u(acc1, (uint)__shfl_xor((int)acc1, s, 64));
            acc2 = hmax2u(acc2, (uint)__shfl_xor((int)acc2, s, 64));
            acc3 = hmax2u(acc3, (uint)__shfl_xor((int)acc3, s, 64));
        }
        if (g == 0) {
            uint a[4] = {acc0, acc1, acc2, acc3};
#pragma unroll
            for (int k = 0; k < 4; ++k) {
                g1t[8 * c8 + 2 * k][wid]     = lo_f(a[k]);
                g1t[8 * c8 + 2 * k + 1][wid] = hi_f(a[k]);
            }
        }
    }
    // ---- pool 2: first 128 -> max of fb. 4 rows per dwordx4 instr ----
    {
        const uint4* fbb = (const uint4*)(fb + (size_t)b * NPTS * 128);
        int g = lane >> 4, c8 = lane & 15;
        uint acc0 = 0, acc1 = 0, acc2 = 0, acc3 = 0;
        int it2 = (c2 + 3) >> 2;
        for (int j = 0; j < it2; ++j) {
            int idx = min(j * 4 + g, c2 - 1);
            int row = nbr[wid][idx];
            uint4 rr = fbb[row * 16 + c8];
            acc0 = hmax2u(acc0, rr.x);
            acc1 = hmax2u(acc1, rr.y);
            acc2 = hmax2u(acc2, rr.z);
            acc3 = hmax2u(acc3, rr.w);
        }
#pragma unroll
        for (int s = 16; s < 64; s <<= 1) {
            acc0 = hmax2u(acc0, (uint)__shfl_xor((int)acc0, s, 64));
            acc1 = hmax2u(acc1, (uint)__shfl_xor((int)acc1, s, 64));
            acc2 = hmax2u(acc2, (uint)__shfl_xor((int)acc2, s, 64));
            acc3 = hmax2u(acc3, (uint)__shfl_xor((int)acc3, s, 64));
        }
        if (g == 0) {
            uint a[4] = {acc0, acc1, acc2, acc3};
#pragma unroll
            for (int k = 0; k < 4; ++k) {
                g2t[8 * c8 + 2 * k][wid]     = lo_f(a[k]);
                g2t[8 * c8 + 2 * k + 1][wid] = hi_f(a[k]);
            }
        }
    }
    __syncthreads();

    // ---- cooperative coalesced stores ----
    {
        int ch = tid >> 4, pt = tid & 15;
        v[((size_t)b * 128 + 64 + ch) * NPTS + i0 + pt] = g1t[ch][pt];
    }
#pragma unroll
    for (int r = 0; r < 2; ++r) {
        int idx = r * 1024 + tid;
        int ch = idx >> 4, pt = idx & 15;
        out[((size_t)b * 384 + 256 + ch) * NPTS + i0 + pt] = g2t[ch][pt];
    }
}

// ---------------- K3: 256x128 pointwise conv (register-tiled GEMM) ----------------
__global__ __launch_bounds__(256) void k_conv2(
    const float* __restrict__ v, const float* __restrict__ Wc2,
    const float* __restrict__ bc2, float* __restrict__ out)
{
    __shared__ float vs[128 * 32];    // 16KB [k][n]
    __shared__ float ws[256 * 33];    // 33KB [o][kk-chunk], +1 pad
    int b = blockIdx.x & 7;           // batch-per-XCD affinity
    int nt = (blockIdx.x >> 3) << 5;  // 32-point tile
    int t = threadIdx.x;
    int n_t = t & 3, o_t = t >> 2;

    const float* vb = v + (size_t)b * 128 * NPTS + nt;
#pragma unroll
    for (int r = 0; r < 4; ++r) {
        int j = r * 256 + t; int k = j >> 3, n4 = j & 7;
        *(float4*)&vs[k * 32 + n4 * 4] = *(const float4*)(vb + (size_t)k * NPTS + n4 * 4);
    }

    float acc[4][8];
#pragma unroll
    for (int r = 0; r < 4; ++r) {
        float bb = bc2[o_t * 4 + r];
#pragma unroll
        for (int n = 0; n < 8; ++n) acc[r][n] = bb;
    }

    for (int kc = 0; kc < 128; kc += 32) {
        __syncthreads();
#pragma unroll
        for (int r = 0; r < 8; ++r) {
            int j = r * 256 + t; int o = j >> 3, c = j & 7;
            float4 wv = *(const float4*)(Wc2 + (size_t)o * 128 + kc + c * 4);
            ws[o * 33 + c * 4 + 0] = wv.x;
            ws[o * 33 + c * 4 + 1] = wv.y;
            ws[o * 33 + c * 4 + 2] = wv.z;
            ws[o * 33 + c * 4 + 3] = wv.w;
        }
        __syncthreads();
#pragma unroll 4
        for (int kk = 0; kk < 32; ++kk) {
            float4 va = *(float4*)&vs[(kc + kk) * 32 + n_t * 8];
            float4 vb4 = *(float4*)&vs[(kc + kk) * 32 + n_t * 8 + 4];
            float vv[8] = {va.x, va.y, va.z, va.w, vb4.x, vb4.y, vb4.z, vb4.w};
            float ww[4];
#pragma unroll
            for (int r = 0; r < 4; ++r) ww[r] = ws[(o_t * 4 + r) * 33 + kk];
#pragma unroll
            for (int r = 0; r < 4; ++r)
#pragma unroll
                for (int n = 0; n < 8; ++n)
                    acc[r][n] = fmaf(ww[r], vv[n], acc[r][n]);
        }
    }

    float* ob = out + ((size_t)b * 384 + o_t * 4) * NPTS + nt + n_t * 8;
#pragma unroll
    for (int r = 0; r < 4; ++r) {
        float4 s0, s1;
        s0.x = fmaxf(0.f, acc[r][0]); s0.y = fmaxf(0.f, acc[r][1]);
        s0.z = fmaxf(0.f, acc[r][2]); s0.w = fmaxf(0.f, acc[r][3]);
        s1.x = fmaxf(0.f, acc[r][4]); s1.y = fmaxf(0.f, acc[r][5]);
        s1.z = fmaxf(0.f, acc[r][6]); s1.w = fmaxf(0.f, acc[r][7]);
        *(float4*)(ob + (size_t)r * NPTS) = s0;
        *(float4*)(ob + (size_t)r * NPTS + 4) = s1;
    }
}

extern "C" void kernel_launch(void* const* d_in, const int* in_sizes, int n_in,
                              void* d_out, int out_size, void* d_ws, size_t ws_size,
                              hipStream_t stream) {
    const float* X   = (const float*)d_in[0];
    const float* W1a = (const float*)d_in[1];
    const float* b1a = (const float*)d_in[2];
    const float* W2a = (const float*)d_in[3];
    const float* b2a = (const float*)d_in[4];
    const float* W1b = (const float*)d_in[5];
    const float* b1b = (const float*)d_in[6];
    const float* W2b = (const float*)d_in[7];
    const float* b2b = (const float*)d_in[8];
    const float* Wc1 = (const float*)d_in[9];
    const float* bc1 = (const float*)d_in[10];
    const float* Wc2 = (const float*)d_in[11];
    const float* bc2 = (const float*)d_in[12];
    float* out = (float*)d_out;

    // workspace: fa(half) 2MB | fb(half) 4MB | v(f32) 8MB
    __half* fa = (__half*)d_ws;
    __half* fb = fa + (size_t)NB * NPTS * 64;
    float*  v  = (float*)(fb + (size_t)NB * NPTS * 128);

    k_features<<<NB * NPTS / 64, 512, 0, stream>>>(X, W1a, b1a, W2a, b2a,
                                                   W1b, b1b, W2b, b2b, Wc1, bc1,
                                                   fa, fb, v);
    k_neighbors<<<NB * NPTS / 16, 1024, 0, stream>>>(X, fa, fb, v, out);
    k_conv2<<<NB * (NPTS / 32), 256, 0, stream>>>(v, Wc2, bc2, out);
}

// Round 8
// 176.629 us; speedup vs baseline: 1.9379x; 1.0985x over previous
//
#include <hip/hip_runtime.h>
#include <hip/hip_fp16.h>
#include <cstdint>

#define NPTS 2048
#define NB 8
// float32 of (0.45*0.45 computed in float64) -- matches jnp/np scalar cast.
// NOTE: 0.45f*0.45f is 1 ulp LOWER; do not use it.
#define R2C 0.2025f

__device__ __forceinline__ float fmul(float a, float b) { return __fmul_rn(a, b); }
__device__ __forceinline__ float fadd(float a, float b) { return __fadd_rn(a, b); }

// packed fp16 max (header lacks __hmax2 on gfx950; ISA has v_pk_max_f16)
__device__ __forceinline__ uint hmax2u(uint a, uint b) {
    uint r;
    asm volatile("v_pk_max_f16 %0, %1, %2" : "=v"(r) : "v"(a), "v"(b));
    return r;
}
__device__ __forceinline__ float lo_f(uint u) {
    __half h = __ushort_as_half((unsigned short)(u & 0xffff));
    return __half2float(h);
}
__device__ __forceinline__ float hi_f(uint u) {
    __half h = __ushort_as_half((unsigned short)(u >> 16));
    return __half2float(h);
}

// ---------------- K1: per-point features (unchanged from R7) ----------------
__global__ __launch_bounds__(512, 4) void k_features(
    const float* __restrict__ X,
    const float* __restrict__ W1a, const float* __restrict__ b1a,
    const float* __restrict__ W2a, const float* __restrict__ b2a,
    const float* __restrict__ W1b, const float* __restrict__ b1b,
    const float* __restrict__ W2b, const float* __restrict__ b2b,
    const float* __restrict__ Wc1, const float* __restrict__ bc1,
    __half* __restrict__ fa, __half* __restrict__ fb, float* __restrict__ v)
{
    __shared__ float fat[64 * 33];   // 64 pts x 32 dwords (64 half ch), pad 33
    __shared__ float fbt[64 * 67];   // 64 pts x 64 dwords (128 half ch), pad 67
    int tid = threadIdx.x;
    int q = __builtin_amdgcn_readfirstlane(tid >> 6);   // wave 0..7 (SGPR)
    int lane = tid & 63;
    int pbase = blockIdx.x * 64;
    int p = pbase + lane;
    int b = p >> 11, i = p & 2047;

    float x0 = X[p * 3 + 0], x1 = X[p * 3 + 1], x2 = X[p * 3 + 2];

    float h[64];
#pragma unroll
    for (int o = 0; o < 32; ++o)
        h[o] = fmaxf(0.f, x0 * W1a[o * 3] + x1 * W1a[o * 3 + 1] + x2 * W1a[o * 3 + 2] + b1a[o]);
#pragma unroll
    for (int oo = 0; oo < 8; oo += 2) {
        int o = q * 8 + oo;
        float a0 = b2a[o], a1 = b2a[o + 1];
#pragma unroll
        for (int k = 0; k < 32; ++k) {
            a0 = fmaf(h[k], W2a[o * 32 + k], a0);
            a1 = fmaf(h[k], W2a[(o + 1) * 32 + k], a1);
        }
        __half2 hh = __floats2half2_rn(fmaxf(0.f, a0), fmaxf(0.f, a1));
        fat[lane * 33 + q * 4 + (oo >> 1)] = *(float*)&hh;
    }
#pragma unroll
    for (int o = 0; o < 64; ++o)
        h[o] = fmaxf(0.f, x0 * W1b[o * 3] + x1 * W1b[o * 3 + 1] + x2 * W1b[o * 3 + 2] + b1b[o]);
#pragma unroll
    for (int oo = 0; oo < 16; oo += 2) {
        int o = q * 16 + oo;
        float a0 = b2b[o], a1 = b2b[o + 1];
#pragma unroll
        for (int k = 0; k < 64; ++k) {
            a0 = fmaf(h[k], W2b[o * 64 + k], a0);
            a1 = fmaf(h[k], W2b[(o + 1) * 64 + k], a1);
        }
        __half2 hh = __floats2half2_rn(fmaxf(0.f, a0), fmaxf(0.f, a1));
        fbt[lane * 67 + q * 8 + (oo >> 1)] = *(float*)&hh;
    }
    float* vb = v + (size_t)b * 128 * NPTS + i;
#pragma unroll
    for (int oo = 0; oo < 8; ++oo) {
        int o = q * 8 + oo;
        vb[(size_t)o * NPTS] =
            fmaxf(0.f, x0 * Wc1[o * 3] + x1 * Wc1[o * 3 + 1] + x2 * Wc1[o * 3 + 2] + bc1[o]);
    }
    __syncthreads();

    uint* fau = (uint*)fa;
#pragma unroll
    for (int r = 0; r < 4; ++r) {
        int idx = r * 512 + tid;
        int pt = idx >> 5, j = idx & 31;
        fau[((size_t)(pbase + pt)) * 32 + j] = *(uint*)&fat[pt * 33 + j];
    }
    uint* fbu = (uint*)fb;
#pragma unroll
    for (int r = 0; r < 8; ++r) {
        int idx = r * 512 + tid;
        int pt = idx >> 6, j = idx & 63;
        fbu[((size_t)(pbase + pt)) * 64 + j] = *(uint*)&fbt[pt * 67 + j];
    }
}

// ---------------- K2: ball query + neighborhood max-pool (fp16 features) ----------------
// Pools now FIXED trip count (c1/c2 are ~always saturated: avg ~500 in-radius
// neighbors for r=0.45 in unit cube), 8 loads batched in flight per group ->
// latency-hidden, L2-BW-bound. Clamped duplicate rows are max-invariant.
__global__ __launch_bounds__(1024) void k_neighbors(
    const float* __restrict__ X, const __half* __restrict__ fa,
    const __half* __restrict__ fb, float* __restrict__ v, float* __restrict__ out)
{
    __shared__ float4 xs4[NPTS];                  // 32KB {x,y,z,|y|^2}
    __shared__ unsigned short nbr[16][128];       // 4KB
    __shared__ float g1t[64][17];                 // [ch][pt]
    __shared__ float g2t[128][17];                // [ch][pt]
    int tid = threadIdx.x;
    int wid = tid >> 6, lane = tid & 63;
    int b = blockIdx.x & 7;                       // batch-per-XCD L2 affinity
    int i0 = (blockIdx.x >> 3) * 16;
    int i = i0 + wid;                             // this wave's point

    const float* Xb = X + (size_t)b * NPTS * 3;
    for (int t = tid; t < NPTS; t += 1024) {
        float y0 = Xb[3 * t], y1 = Xb[3 * t + 1], y2 = Xb[3 * t + 2];
        float mm = fadd(fadd(fmul(y0, y0), fmul(y1, y1)), fmul(y2, y2));
        xs4[t] = make_float4(y0, y1, y2, mm);
    }
    __syncthreads();

    float4 cc = xs4[i];
    float n0 = cc.x, n1 = cc.y, n2 = cc.z, nn = cc.w;

    // 32 ballot words; lane w keeps word w (exact numpy arithmetic, no FMA)
    unsigned long long myword = 0;
    for (int w = 0; w < 32; ++w) {
        float4 y = xs4[(w << 6) | lane];
        float dot = fadd(fadd(fmul(n0, y.x), fmul(n1, y.y)), fmul(n2, y.z));
        float d   = fadd(fadd(fmul(-2.0f, dot), nn), y.w);
        unsigned long long bm = __ballot(!(d > R2C));
        if (lane == w) myword = bm;
    }

    // parallel decode: prefix-sum of per-word popcounts -> rank base
    int cnt = (lane < 32) ? __popcll(myword) : 0;
    int incl = cnt;
#pragma unroll
    for (int d = 1; d < 32; d <<= 1) {
        int t = __shfl_up(incl, d, 64);
        if (lane >= d) incl += t;
    }
    int pre = incl - cnt;
    if (lane < 32 && cnt && pre < 128) {
        unsigned long long word = myword;
        int r = pre;
        while (word && r < 128) {
            int pb = __builtin_ctzll(word);
            word &= word - 1;
            nbr[wid][r++] = (unsigned short)((lane << 6) | pb);
        }
    }
    int total = __shfl(incl, 31, 64);
    int c1 = min(total, 64);     // >=1 (self always in radius)
    int c2 = min(total, 128);
    __syncthreads();

    // ---- pool 1: first 64 -> max of fa. 8 rows/instr, 8 loads in flight ----
    {
        const uint4* fab = (const uint4*)(fa + (size_t)b * NPTS * 64);
        int g = lane >> 3, c8 = lane & 7;         // row-in-group, channel-octet
        int cl = c1 - 1;
        uint4 r[8];
#pragma unroll
        for (int j = 0; j < 8; ++j) {
            int idx = j * 8 + g; idx = idx > cl ? cl : idx;
            int row = nbr[wid][idx];
            r[j] = fab[row * 8 + c8];
        }
        uint acc0 = 0, acc1 = 0, acc2 = 0, acc3 = 0;   // relu outputs >= 0
#pragma unroll
        for (int j = 0; j < 8; ++j) {
            acc0 = hmax2u(acc0, r[j].x);
            acc1 = hmax2u(acc1, r[j].y);
            acc2 = hmax2u(acc2, r[j].z);
            acc3 = hmax2u(acc3, r[j].w);
        }
#pragma unroll
        for (int s = 8; s < 64; s <<= 1) {
            acc0 = hmax2u(acc0, (uint)__shfl_xor((int)acc0, s, 64));
            acc1 = hmax2u(acc1, (uint)__shfl_xor((int)acc1, s, 64));
            acc2 = hmax2u(acc2, (uint)__shfl_xor((int)acc2, s, 64));
            acc3 = hmax2u(acc3, (uint)__shfl_xor((int)acc3, s, 64));
        }
        if (g == 0) {
            uint a[4] = {acc0, acc1, acc2, acc3};
#pragma unroll
            for (int k = 0; k < 4; ++k) {
                g1t[8 * c8 + 2 * k][wid]     = lo_f(a[k]);
                g1t[8 * c8 + 2 * k + 1][wid] = hi_f(a[k]);
            }
        }
    }
    // ---- pool 2: first 128 -> max of fb. 4 rows/instr, 8 loads in flight ----
    {
        const uint4* fbb = (const uint4*)(fb + (size_t)b * NPTS * 128);
        int g = lane >> 4, c8 = lane & 15;
        int cl = c2 - 1;
        uint acc0 = 0, acc1 = 0, acc2 = 0, acc3 = 0;
#pragma unroll
        for (int jo = 0; jo < 32; jo += 8) {
            uint4 r[8];
#pragma unroll
            for (int jj = 0; jj < 8; ++jj) {
                int idx = (jo + jj) * 4 + g; idx = idx > cl ? cl : idx;
                int row = nbr[wid][idx];
                r[jj] = fbb[row * 16 + c8];
            }
#pragma unroll
            for (int jj = 0; jj < 8; ++jj) {
                acc0 = hmax2u(acc0, r[jj].x);
                acc1 = hmax2u(acc1, r[jj].y);
                acc2 = hmax2u(acc2, r[jj].z);
                acc3 = hmax2u(acc3, r[jj].w);
            }
        }
#pragma unroll
        for (int s = 16; s < 64; s <<= 1) {
            acc0 = hmax2u(acc0, (uint)__shfl_xor((int)acc0, s, 64));
            acc1 = hmax2u(acc1, (uint)__shfl_xor((int)acc1, s, 64));
            acc2 = hmax2u(acc2, (uint)__shfl_xor((int)acc2, s, 64));
            acc3 = hmax2u(acc3, (uint)__shfl_xor((int)acc3, s, 64));
        }
        if (g == 0) {
            uint a[4] = {acc0, acc1, acc2, acc3};
#pragma unroll
            for (int k = 0; k < 4; ++k) {
                g2t[8 * c8 + 2 * k][wid]     = lo_f(a[k]);
                g2t[8 * c8 + 2 * k + 1][wid] = hi_f(a[k]);
            }
        }
    }
    __syncthreads();

    // ---- cooperative coalesced stores ----
    {
        int ch = tid >> 4, pt = tid & 15;
        v[((size_t)b * 128 + 64 + ch) * NPTS + i0 + pt] = g1t[ch][pt];
    }
#pragma unroll
    for (int r = 0; r < 2; ++r) {
        int idx = r * 1024 + tid;
        int ch = idx >> 4, pt = idx & 15;
        out[((size_t)b * 384 + 256 + ch) * NPTS + i0 + pt] = g2t[ch][pt];
    }
}

// ---------------- K3: 256x128 pointwise conv (unchanged from R7) ----------------
__global__ __launch_bounds__(256) void k_conv2(
    const float* __restrict__ v, const float* __restrict__ Wc2,
    const float* __restrict__ bc2, float* __restrict__ out)
{
    __shared__ float vs[128 * 32];    // 16KB [k][n]
    __shared__ float ws[256 * 33];    // 33KB [o][kk-chunk], +1 pad
    int b = blockIdx.x & 7;           // batch-per-XCD affinity
    int nt = (blockIdx.x >> 3) << 5;  // 32-point tile
    int t = threadIdx.x;
    int n_t = t & 3, o_t = t >> 2;

    const float* vb = v + (size_t)b * 128 * NPTS + nt;
#pragma unroll
    for (int r = 0; r < 4; ++r) {
        int j = r * 256 + t; int k = j >> 3, n4 = j & 7;
        *(float4*)&vs[k * 32 + n4 * 4] = *(const float4*)(vb + (size_t)k * NPTS + n4 * 4);
    }

    float acc[4][8];
#pragma unroll
    for (int r = 0; r < 4; ++r) {
        float bb = bc2[o_t * 4 + r];
#pragma unroll
        for (int n = 0; n < 8; ++n) acc[r][n] = bb;
    }

    for (int kc = 0; kc < 128; kc += 32) {
        __syncthreads();
#pragma unroll
        for (int r = 0; r < 8; ++r) {
            int j = r * 256 + t; int o = j >> 3, c = j & 7;
            float4 wv = *(const float4*)(Wc2 + (size_t)o * 128 + kc + c * 4);
            ws[o * 33 + c * 4 + 0] = wv.x;
            ws[o * 33 + c * 4 + 1] = wv.y;
            ws[o * 33 + c * 4 + 2] = wv.z;
            ws[o * 33 + c * 4 + 3] = wv.w;
        }
        __syncthreads();
#pragma unroll 4
        for (int kk = 0; kk < 32; ++kk) {
            float4 va = *(float4*)&vs[(kc + kk) * 32 + n_t * 8];
            float4 vb4 = *(float4*)&vs[(kc + kk) * 32 + n_t * 8 + 4];
            float vv[8] = {va.x, va.y, va.z, va.w, vb4.x, vb4.y, vb4.z, vb4.w};
            float ww[4];
#pragma unroll
            for (int r = 0; r < 4; ++r) ww[r] = ws[(o_t * 4 + r) * 33 + kk];
#pragma unroll
            for (int r = 0; r < 4; ++r)
#pragma unroll
                for (int n = 0; n < 8; ++n)
                    acc[r][n] = fmaf(ww[r], vv[n], acc[r][n]);
        }
    }

    float* ob = out + ((size_t)b * 384 + o_t * 4) * NPTS + nt + n_t * 8;
#pragma unroll
    for (int r = 0; r < 4; ++r) {
        float4 s0, s1;
        s0.x = fmaxf(0.f, acc[r][0]); s0.y = fmaxf(0.f, acc[r][1]);
        s0.z = fmaxf(0.f, acc[r][2]); s0.w = fmaxf(0.f, acc[r][3]);
        s1.x = fmaxf(0.f, acc[r][4]); s1.y = fmaxf(0.f, acc[r][5]);
        s1.z = fmaxf(0.f, acc[r][6]); s1.w = fmaxf(0.f, acc[r][7]);
        *(float4*)(ob + (size_t)r * NPTS) = s0;
        *(float4*)(ob + (size_t)r * NPTS + 4) = s1;
    }
}

extern "C" void kernel_launch(void* const* d_in, const int* in_sizes, int n_in,
                              void* d_out, int out_size, void* d_ws, size_t ws_size,
                              hipStream_t stream) {
    const float* X   = (const float*)d_in[0];
    const float* W1a = (const float*)d_in[1];
    const float* b1a = (const float*)d_in[2];
    const float* W2a = (const float*)d_in[3];
    const float* b2a = (const float*)d_in[4];
    const float* W1b = (const float*)d_in[5];
    const float* b1b = (const float*)d_in[6];
    const float* W2b = (const float*)d_in[7];
    const float* b2b = (const float*)d_in[8];
    const float* Wc1 = (const float*)d_in[9];
    const float* bc1 = (const float*)d_in[10];
    const float* Wc2 = (const float*)d_in[11];
    const float* bc2 = (const float*)d_in[12];
    float* out = (float*)d_out;

    // workspace: fa(half) 2MB | fb(half) 4MB | v(f32) 8MB
    __half* fa = (__half*)d_ws;
    __half* fb = fa + (size_t)NB * NPTS * 64;
    float*  v  = (float*)(fb + (size_t)NB * NPTS * 128);

    k_features<<<NB * NPTS / 64, 512, 0, stream>>>(X, W1a, b1a, W2a, b2a,
                                                   W1b, b1b, W2b, b2b, Wc1, bc1,
                                                   fa, fb, v);
    k_neighbors<<<NB * NPTS / 16, 1024, 0, stream>>>(X, fa, fb, v, out);
    k_conv2<<<NB * (NPTS / 32), 256, 0, stream>>>(v, Wc2, bc2, out);
}